// Round 5
// baseline (589.982 us; speedup 1.0000x reference)
//
#include <hip/hip_runtime.h>
#include <math.h>

#define NN 10000
#define EE 100000
#define EPB 8           // edges per block
#define AST 1000        // sA row stride (ushorts): 2000B rows -> 8 distinct banks
#define YSTH 456        // sY row stride (ushorts, bf16)

// staged-input segment offsets within an sA row (ushort index)
#define SEG0 0          // in0 (288)
#define SEGP1 288       // x1[:,:,2](96) + x2[:,:,3](96)
#define SEGM1 480       // x1[:,:,0](96) + x2[:,:,1](96)
#define SEGP2 672       // x2[:,:,4](96)
#define SEGM2 768       // x2[:,:,0](96)
#define SEGL 864        // latents (128)  -> row used = 992

// sY per-edge layout (bf16)
#define Y0o   0
#define Y10o  96
#define Y20o  128
#define Y1Po  160
#define Y1Mo  192
#define Y2P1o 224
#define Y2M1o 256
#define Y2P2o 288
#define Y2M2o 320
#define WENVo 352

// packed-weight region offsets (ushort index)
#define PK1 0           // [10][9][64][8]   160x288
#define PK2 46080       // [8][12][64][8]   128x384
#define PK3 95232       // [4][6][64][8]    64x192
#define PK4 107520      // [6][4][64][8]    96x128
#define PKP 119808      // [3][2][64][8]    wp0/wp1/wp2 32x32
#define PKTOT 122880
#define NRM_FLOATS (NN*288)

#define SQ3F  1.7320508075688772f
#define S0F   0.05892556509887896f
#define S1F   0.07216878364870323f
#define S2F   0.10206207261596575f
#define SEF   0.08838834764831845f
#define SCF   0.17677669529663687f
#define COLDF 0.8944271909999159f
#define COEFF 0.1414213562373095f

typedef __attribute__((ext_vector_type(8))) short bf16x8;
typedef __attribute__((ext_vector_type(4))) float f32x4;

__device__ __forceinline__ ushort f2bf(float f) {
    union { float f; unsigned u; } v; v.f = f;
    unsigned r = v.u + 0x7fff + ((v.u >> 16) & 1);
    return (ushort)(r >> 16);
}
__device__ __forceinline__ float bf2f(ushort u) {
    union { unsigned u; float f; } v; v.u = (unsigned)u << 16; return v.f;
}

// planar layout: l0 [0..31], x1 planes 32+32*m+c (m<3), x2 planes 128+32*m+c (m<5)
__device__ __forceinline__ int planar(int k) {
    if (k < 32) return k;
    if (k < 128) { int c = (k - 32) / 3, m = (k - 32) % 3; return 32 + 32*m + c; }
    int c = (k - 128) / 5, m = (k - 128) % 5; return 128 + 32*m + c;
}

// ---------------- weight pre-pack: MFMA B-frag order, bf16 ----------------
__global__ __launch_bounds__(256) void pack_k(
    const float* __restrict__ w0s, const float* __restrict__ w01, const float* __restrict__ w02,
    const float* __restrict__ wr11, const float* __restrict__ wi11,
    const float* __restrict__ wr12, const float* __restrict__ wi12,
    const float* __restrict__ wr22, const float* __restrict__ wi22,
    const float* __restrict__ wenv,
    const float* __restrict__ wp0, const float* __restrict__ wp1, const float* __restrict__ wp2,
    ushort* __restrict__ pk)
{
    int i = blockIdx.x * 256 + threadIdx.x;
    if (i >= PKTOT) return;
    float val;
    if (i < PK2) {
        int idx = i - PK1;
        int tile = idx / 4608, rem = idx % 4608;
        int chunk = rem / 512, rem2 = rem % 512;
        int lane = rem2 / 8, j = rem2 % 8;
        int col = tile * 16 + (lane & 15);
        int k = chunk * 32 + (lane >> 4) * 8 + j;
        if (col < 96)       val = w0s[col * 288 + k];
        else if (col < 128) val = w01[(col - 96) * 288 + k];
        else                val = w02[(col - 128) * 288 + k];
    } else if (i < PK3) {
        int idx = i - PK2;
        int tile = idx / 6144, rem = idx % 6144;
        int chunk = rem / 512, rem2 = rem % 512;
        int lane = rem2 / 8, j = rem2 % 8;
        int col = tile * 16 + (lane & 15);
        int k = chunk * 32 + (lane >> 4) * 8 + j;
        int grp = col >> 5, c = col & 31;
        if (k < 192) {
            val = (grp == 0) ? wr11[c*192 + k] : (grp == 1) ? wi11[c*192 + k]
                : (grp == 2) ? wr12[c*192 + k] : wi12[c*192 + k];
        } else {
            int kk = k - 192;
            val = (grp == 0) ? -wi11[c*192 + kk] : (grp == 1) ? wr11[c*192 + kk]
                : (grp == 2) ? -wi12[c*192 + kk] : wr12[c*192 + kk];
        }
    } else if (i < PK4) {
        int idx = i - PK3;
        int tile = idx / 3072, rem = idx % 3072;
        int chunk = rem / 512, rem2 = rem % 512;
        int lane = rem2 / 8, j = rem2 % 8;
        int col = tile * 16 + (lane & 15);
        int k = chunk * 32 + (lane >> 4) * 8 + j;
        int grp = col >> 5, c = col & 31;
        if (k < 96) val = grp ? wi22[c*96 + k] : wr22[c*96 + k];
        else        val = grp ? wr22[c*96 + k - 96] : -wi22[c*96 + k - 96];
    } else if (i < PKP) {
        int idx = i - PK4;
        int tile = idx / 2048, rem = idx % 2048;
        int chunk = rem / 512, rem2 = rem % 512;
        int lane = rem2 / 8, j = rem2 % 8;
        int col = tile * 16 + (lane & 15);
        int k = chunk * 32 + (lane >> 4) * 8 + j;
        val = wenv[col * 128 + k];
    } else {
        int idx = i - PKP;
        int wpi = idx / 1024, rem = idx % 1024;
        int ct = rem / 512, rem2 = rem % 512;
        int lane = rem2 / 8, j = rem2 % 8;
        int col = ct * 16 + (lane & 15);
        int k = (lane >> 4) * 8 + j;
        const float* w = (wpi == 0) ? wp0 : (wpi == 1) ? wp1 : wp2;
        val = w[col * 32 + k];
    }
    pk[i] = f2bf(val);
}

// ---------------- node SLN -> planar nrm ----------------
__global__ __launch_bounds__(256) void node_norm_k(
    const float* __restrict__ nf,
    const float* __restrict__ g0, const float* __restrict__ b0,
    const float* __restrict__ g1, const float* __restrict__ g2,
    float* __restrict__ nrm, float* __restrict__ out)
{
    int row = blockIdx.x * 4 + (threadIdx.x >> 6);
    if (row >= NN) return;
    int lane = threadIdx.x & 63;
    const float* r = nf + (size_t)row * 288;
    float v0 = r[lane];
    float v1 = r[lane + 64];
    float v2 = r[lane + 128];
    float v3 = r[lane + 192];
    float v4 = (lane < 32) ? r[lane + 256] : 0.f;
    float s0 = 0.f, s0q = 0.f, q1 = 0.f, q2 = 0.f;
    if (lane < 32) { s0 = v0; s0q = v0*v0; } else { q1 = v0*v0; }
    q1 += v1*v1;
    q2 += v2*v2 + v3*v3 + v4*v4;
#pragma unroll
    for (int m = 1; m < 64; m <<= 1) {
        s0  += __shfl_xor(s0, m);
        s0q += __shfl_xor(s0q, m);
        q1  += __shfl_xor(q1, m);
        q2  += __shfl_xor(q2, m);
    }
    float mu  = s0 * (1.f/32.f);
    float var = s0q * (1.f/32.f) - mu*mu;
    float rs0 = rsqrtf(var + 1e-8f);
    float rv  = 0.5f * (q1 * (1.f/96.f) + q2 * (1.f/160.f));
    float rs  = rsqrtf(rv + 1e-8f);
    float* nr = nrm + (size_t)row * 288;
    float* orow = out + (size_t)row * 288;
    {
        float res;
        if (lane < 32) res = (v0 - mu) * rs0 * g0[lane] + b0[lane];
        else { int c = (lane - 32) / 3; res = v0 * rs * g1[c]; }
        nr[planar(lane)] = res; orow[lane] = COLDF * v0;
    }
    { int k = lane + 64;  int c = (k - 32) / 3;  nr[planar(k)] = v1 * rs * g1[c]; orow[k] = COLDF * v1; }
    { int k = lane + 128; int c = (k - 128) / 5; nr[planar(k)] = v2 * rs * g2[c]; orow[k] = COLDF * v2; }
    { int k = lane + 192; int c = (k - 128) / 5; nr[planar(k)] = v3 * rs * g2[c]; orow[k] = COLDF * v3; }
    if (lane < 32) { int k = lane + 256; int c = (k - 128) / 5; nr[planar(k)] = v4 * rs * g2[c]; orow[k] = COLDF * v4; }
}

// ---------------- fused edge kernel: 256 threads / 8 edges ----------------
__global__ __launch_bounds__(256, 6) void edge_k(
    const float* __restrict__ lat, const float* __restrict__ ef,
    const float* __restrict__ evec,
    const int* __restrict__ eidx, const int* __restrict__ act,
    const float* __restrict__ g0e, const float* __restrict__ b0e,
    const float* __restrict__ g1e, const float* __restrict__ g2e,
    const ushort* __restrict__ pk,
    const float* __restrict__ bp0, const float* __restrict__ benv,
    const float* __restrict__ nrm, float* __restrict__ out)
{
    __shared__ __align__(16) ushort sA[EPB * AST];   // 16000 B; reused as A-proj then sP (f32)
    __shared__ __align__(16) ushort sY[EPB * YSTH];  // 7296 B (bf16)
    __shared__ float sD1[EPB][12];
    __shared__ float sD2[EPB][28];
    __shared__ int sAe[EPB], sCtr[EPB], sNbr[EPB];

    const int tid = threadIdx.x;
    const int wv = tid >> 6, lane = tid & 63;

    // ---------------- prefetch edge indices (depth-2 chain, once) ----------------
    if (tid < EPB) {
        int ae = act[blockIdx.x * EPB + tid];
        sAe[tid] = ae;
        sCtr[tid] = eidx[ae];
        sNbr[tid] = eidx[EE + ae];
    }
    __syncthreads();

    // ---------------- prep: wave per edge, 2 iterations ----------------
    for (int it = 0; it < 2; ++it) {
        const int e = it * 4 + wv;
        const int ae = sAe[e];
        const int ctr = sCtr[e], nbr = sNbr[e];
        ushort* row = sA + e * AST;
        ushort* sEb = sY + e * YSTH;   // bf16 planar staging (dead after prep)
        const float* efr = ef + (size_t)ae * 288;

        // --- edge SLN stats (coalesced loads) ---
        float ev0 = efr[lane];
        float ev1 = efr[lane + 64];
        float ev2 = efr[lane + 128];
        float ev3 = efr[lane + 192];
        float ev4 = (lane < 32) ? efr[lane + 256] : 0.f;
        float s0 = 0.f, s0q = 0.f, q1 = 0.f, q2 = 0.f;
        if (lane < 32) { s0 = ev0; s0q = ev0*ev0; } else { q1 = ev0*ev0; }
        q1 += ev1*ev1;
        q2 += ev2*ev2 + ev3*ev3 + ev4*ev4;
#pragma unroll
        for (int m = 1; m < 64; m <<= 1) {
            s0  += __shfl_xor(s0, m);
            s0q += __shfl_xor(s0q, m);
            q1  += __shfl_xor(q1, m);
            q2  += __shfl_xor(q2, m);
        }
        float mu  = s0 * (1.f/32.f);
        float rs0 = rsqrtf(s0q*(1.f/32.f) - mu*mu + 1e-8f);
        float rs  = rsqrtf(0.5f*(q1*(1.f/96.f) + q2*(1.f/160.f)) + 1e-8f);

        // --- stage scaled edge x1/x2 into planar bf16 LDS ---
        if (lane >= 32) { int c = (lane-32)/3, m = (lane-32)%3; sEb[32 + 32*m + c] = f2bf(ev0 * rs * g1e[c]); }
        { int k = lane+64;  int c = (k-32)/3,  m = (k-32)%3;  sEb[32 + 32*m + c]  = f2bf(ev1 * rs * g1e[c]); }
        { int k = lane+128; int c = (k-128)/5, m = (k-128)%5; sEb[128 + 32*m + c] = f2bf(ev2 * rs * g2e[c]); }
        { int k = lane+192; int c = (k-128)/5, m = (k-128)%5; sEb[128 + 32*m + c] = f2bf(ev3 * rs * g2e[c]); }
        if (lane < 32) { int k = lane+256; int c = (k-128)/5, m = (k-128)%5; sEb[128 + 32*m + c] = f2bf(ev4 * rs * g2e[c]); }

        // scalar (l=0) part of in0 + latents
        if (lane < 32) {
            row[SEG0 + 32 + lane] = f2bf((ev0 - mu) * rs0 * g0e[lane] + b0e[lane]);
            row[SEG0 + lane]      = f2bf(nrm[(size_t)ctr*288 + lane]);
            row[SEG0 + 64 + lane] = f2bf(nrm[(size_t)nbr*288 + lane]);
        }
        {
            const float* lr = lat + (size_t)ae * 128;
            row[SEGL + lane]      = f2bf(lr[lane]);
            row[SEGL + 64 + lane] = f2bf(lr[lane + 64]);
        }

        // --- local frame D1 rows (u, n, v) + analytic l=2 Wigner ---
        float vx = evec[3*ae], vy = evec[3*ae+1], vz = evec[3*ae+2];
        float nnv = fmaxf(sqrtf(vx*vx + vy*vy + vz*vz), 1e-9f);
        float nx = vx/nnv, ny = vy/nnv, nz = vz/nnv;
        float ax, az;
        if (fabsf(nx) < 0.9f) { ax = 1.f; az = 0.f; } else { ax = 0.f; az = 1.f; }
        float adn = ax*nx + az*nz;
        float ux = ax - adn*nx, uy = -adn*ny, uz = az - adn*nz;
        float un = fmaxf(sqrtf(ux*ux + uy*uy + uz*uz), 1e-9f);
        ux /= un; uy /= un; uz /= un;
        float wx = uy*nz - uz*ny, wy = uz*nx - ux*nz, wz = ux*ny - uy*nx;

        float d2[5][5];
        d2[0][0] = wz*ux + uz*wx;  d2[0][1] = wx*uy + ux*wy;  d2[0][2] = SQ3F*wy*uy;
        d2[0][3] = wy*uz + uy*wz;  d2[0][4] = wz*uz - wx*ux;
        d2[1][0] = uz*nx + nz*ux;  d2[1][1] = ux*ny + nx*uy;  d2[1][2] = SQ3F*uy*ny;
        d2[1][3] = uy*nz + ny*uz;  d2[1][4] = uz*nz - ux*nx;
        d2[2][0] = SQ3F*nz*nx;     d2[2][1] = SQ3F*nx*ny;     d2[2][2] = 1.5f*ny*ny - 0.5f;
        d2[2][3] = SQ3F*ny*nz;     d2[2][4] = 0.5f*SQ3F*(nz*nz - nx*nx);
        d2[3][0] = nz*wx + wz*nx;  d2[3][1] = nx*wy + wx*ny;  d2[3][2] = SQ3F*ny*wy;
        d2[3][3] = ny*wz + wy*nz;  d2[3][4] = nz*wz - nx*wx;
        d2[4][0] = wz*wx - uz*ux;  d2[4][1] = wx*wy - ux*uy;  d2[4][2] = 0.5f*SQ3F*(wy*wy - uy*uy);
        d2[4][3] = wy*wz - uy*uz;  d2[4][4] = 0.5f*(wz*wz - uz*uz - wx*wx + ux*ux);

        if (lane == 0) {
            sD1[e][0] = ux; sD1[e][1] = uy; sD1[e][2] = uz;
            sD1[e][3] = nx; sD1[e][4] = ny; sD1[e][5] = nz;
            sD1[e][6] = wx; sD1[e][7] = wy; sD1[e][8] = wz;
#pragma unroll
            for (int n = 0; n < 5; ++n)
#pragma unroll
                for (int m = 0; m < 5; ++m) sD2[e][5*n + m] = d2[n][m];
        }

        asm volatile("s_waitcnt lgkmcnt(0)" ::: "memory");

        // --- rotate l=1/l=2 channels into bf16 staged layout ---
#pragma unroll
        for (int half = 0; half < 2; ++half) {
            const int cc = lane + 64*half;
            if (cc < 96) {
                float x1v[3], x2v[5];
                if (cc < 32) {
                    const float* b = nrm + (size_t)ctr * 288;
#pragma unroll
                    for (int m = 0; m < 3; ++m) x1v[m] = b[32 + 32*m + cc];
#pragma unroll
                    for (int m = 0; m < 5; ++m) x2v[m] = b[128 + 32*m + cc];
                } else if (cc < 64) {
                    const int c = cc - 32;
#pragma unroll
                    for (int m = 0; m < 3; ++m) x1v[m] = bf2f(sEb[32 + 32*m + c]);
#pragma unroll
                    for (int m = 0; m < 5; ++m) x2v[m] = bf2f(sEb[128 + 32*m + c]);
                } else {
                    const float* b = nrm + (size_t)nbr * 288;
                    const int c = cc - 64;
#pragma unroll
                    for (int m = 0; m < 3; ++m) x1v[m] = b[32 + 32*m + c];
#pragma unroll
                    for (int m = 0; m < 5; ++m) x2v[m] = b[128 + 32*m + c];
                }
                float r0 = ux*x1v[0] + uy*x1v[1] + uz*x1v[2];
                float r1 = nx*x1v[0] + ny*x1v[1] + nz*x1v[2];
                float r2 = wx*x1v[0] + wy*x1v[1] + wz*x1v[2];
                float t[5];
#pragma unroll
                for (int m = 0; m < 5; ++m)
                    t[m] = d2[m][0]*x2v[0] + d2[m][1]*x2v[1] + d2[m][2]*x2v[2]
                         + d2[m][3]*x2v[3] + d2[m][4]*x2v[4];
                row[SEG0 + 96  + cc] = f2bf(r1);
                row[SEG0 + 192 + cc] = f2bf(t[2]);
                row[SEGP1 + cc]      = f2bf(r2);
                row[SEGP1 + 96 + cc] = f2bf(t[3]);
                row[SEGM1 + cc]      = f2bf(r0);
                row[SEGM1 + 96 + cc] = f2bf(t[1]);
                row[SEGP2 + cc]      = f2bf(t[4]);
                row[SEGM2 + cc]      = f2bf(t[0]);
            }
        }
    }
    __syncthreads();

    // ---------------- MFMA GEMM phase: 28 tiles across 4 waves ----------------
    // A rows 8..15 duplicate rows 0..7 (only 8 edges); their outputs are discarded.
    for (int t = wv; t < 28; t += 4) {
        int kbase, nch, yoff, pbase; float scale;
        if (t < 10)      { kbase = SEG0;  nch = 9;  yoff = t*16;          scale = S0F; pbase = PK1 + t*9*512; }
        else if (t < 18) { kbase = SEGP1; nch = 12; yoff = 160+(t-10)*16; scale = S1F; pbase = PK2 + (t-10)*12*512; }
        else if (t < 22) { kbase = SEGP2; nch = 6;  yoff = 288+(t-18)*16; scale = S2F; pbase = PK3 + (t-18)*6*512; }
        else             { kbase = SEGL;  nch = 4;  yoff = 352+(t-22)*16; scale = SEF; pbase = PK4 + (t-22)*4*512; }
        f32x4 acc = {0.f, 0.f, 0.f, 0.f};
        const ushort* pa = sA + (lane & 7) * AST + kbase + (lane >> 4) * 8;
        const ushort* pb = pk + pbase + lane * 8;
        for (int ch = 0; ch < nch; ++ch) {
            bf16x8 a = *reinterpret_cast<const bf16x8*>(pa + ch * 32);
            bf16x8 b = *reinterpret_cast<const bf16x8*>(pb + ch * 512);
            acc = __builtin_amdgcn_mfma_f32_16x16x32_bf16(a, b, acc, 0, 0, 0);
        }
        const int col = yoff + (lane & 15);
        const int r0 = (lane >> 4) * 4;
        if (r0 < EPB) {
            float bv = (t >= 22) ? benv[col - 352] : 0.f;
#pragma unroll
            for (int j = 0; j < 4; ++j)
                sY[(r0 + j) * YSTH + col] = f2bf(acc[j] * scale + bv);
        }
    }
    __syncthreads();

    // ---------------- stage 2a: gates, build gated n-frame A-matrix (96x32 bf16) ----------------
    const int e2 = tid & 7, c = tid >> 3;   // c in 0..31
    const ushort* yrow = sY + e2 * YSTH;
    {
        float y0v = bf2f(yrow[Y0o + c]);
        float scv = y0v / (1.f + expf(-y0v));
        float gg1 = 1.f / (1.f + expf(-bf2f(yrow[Y0o + 32 + c])));
        float gg2 = 1.f / (1.f + expf(-bf2f(yrow[Y0o + 64 + c])));
        // rows: 0-7 silu | 16+8m+e (m<3) y1 gated | 48+8m+e (m<5) y2 gated
        sA[(0  + e2)*32 + c] = f2bf(scv);
        sA[(16 + e2)*32 + c] = f2bf(bf2f(yrow[Y1Mo  + c]) * gg1);
        sA[(24 + e2)*32 + c] = f2bf(bf2f(yrow[Y10o  + c]) * gg1);
        sA[(32 + e2)*32 + c] = f2bf(bf2f(yrow[Y1Po  + c]) * gg1);
        sA[(48 + e2)*32 + c] = f2bf(bf2f(yrow[Y2M2o + c]) * gg2);
        sA[(56 + e2)*32 + c] = f2bf(bf2f(yrow[Y2M1o + c]) * gg2);
        sA[(64 + e2)*32 + c] = f2bf(bf2f(yrow[Y20o  + c]) * gg2);
        sA[(72 + e2)*32 + c] = f2bf(bf2f(yrow[Y2P1o + c]) * gg2);
        sA[(80 + e2)*32 + c] = f2bf(bf2f(yrow[Y2P2o + c]) * gg2);
    }
    __syncthreads();

    // ---------------- proj MFMA: 12 tiles (6 row x 2 col) across 4 waves ----------------
    f32x4 pacc[3];
#pragma unroll
    for (int q = 0; q < 3; ++q) {
        const int tt = wv * 3 + q;
        const int rt = tt >> 1, ct = tt & 1;
        const int wpi = (rt == 0) ? 0 : (rt < 3) ? 1 : 2;
        bf16x8 a = *reinterpret_cast<const bf16x8*>(sA + (rt*16 + (lane & 15))*32 + (lane >> 4)*8);
        bf16x8 b = *reinterpret_cast<const bf16x8*>(pk + PKP + wpi*1024 + ct*512 + lane*8);
        f32x4 z = {0.f, 0.f, 0.f, 0.f};
        pacc[q] = __builtin_amdgcn_mfma_f32_16x16x32_bf16(a, b, z, 0, 0, 0);
    }
    __syncthreads();   // all A reads done -> safe to overwrite sA with sP (f32)

    float* sPf = reinterpret_cast<float*>(sA);
#pragma unroll
    for (int q = 0; q < 3; ++q) {
        const int tt = wv * 3 + q;
        const int rt = tt >> 1, ct = tt & 1;
        const int col = ct*16 + (lane & 15);
#pragma unroll
        for (int j = 0; j < 4; ++j) {
            const int rw = rt*16 + (lane >> 4)*4 + j;
            const bool used = (rw < 8) || (rw >= 16 && rw < 40) || (rw >= 48 && rw < 88);
            if (used) sPf[rw*32 + col] = pacc[q][j];
        }
    }
    __syncthreads();

    // ---------------- stage 2b: rotate-back (3x3,5x5) + env gate + scatter ----------------
    const int d = c;   // 0..31
    float* ob = out + (size_t)sCtr[e2] * 288;
    {
        float wv0g = bf2f(yrow[WENVo + d]);
        float m0v = (sPf[e2*32 + d] * SCF + bp0[d]) * wv0g;
        atomicAdd(ob + d, COEFF * m0v);

        float p1v[3], p2v[5];
#pragma unroll
        for (int m = 0; m < 3; ++m) p1v[m] = sPf[(16 + 8*m + e2)*32 + d];
#pragma unroll
        for (int m = 0; m < 5; ++m) p2v[m] = sPf[(48 + 8*m + e2)*32 + d];

        float wv1g = bf2f(yrow[WENVo + 32 + d]) * SCF;
#pragma unroll
        for (int mm = 0; mm < 3; ++mm) {
            float o = sD1[e2][mm]*p1v[0] + sD1[e2][3+mm]*p1v[1] + sD1[e2][6+mm]*p1v[2];
            atomicAdd(ob + 32 + 3*d + mm, COEFF * (o * wv1g));
        }
        float wv2g = bf2f(yrow[WENVo + 64 + d]) * SCF;
#pragma unroll
        for (int mm = 0; mm < 5; ++mm) {
            float o = sD2[e2][mm]*p2v[0] + sD2[e2][5+mm]*p2v[1] + sD2[e2][10+mm]*p2v[2]
                    + sD2[e2][15+mm]*p2v[3] + sD2[e2][20+mm]*p2v[4];
            atomicAdd(ob + 128 + 5*d + mm, COEFF * (o * wv2g));
        }
    }
}

extern "C" void kernel_launch(void* const* d_in, const int* in_sizes, int n_in,
                              void* d_out, int out_size, void* d_ws, size_t ws_size,
                              hipStream_t stream)
{
    const float* latents = (const float*)d_in[0];
    const float* nf      = (const float*)d_in[1];
    const float* efe     = (const float*)d_in[2];
    const float* evec    = (const float*)d_in[3];
    const int*   eidx    = (const int*)d_in[5];
    const int*   act     = (const int*)d_in[6];
    const float* g0n = (const float*)d_in[7];
    const float* b0n = (const float*)d_in[8];
    const float* g1n = (const float*)d_in[9];
    const float* g2n = (const float*)d_in[10];
    const float* g0e = (const float*)d_in[11];
    const float* b0e = (const float*)d_in[12];
    const float* g1e = (const float*)d_in[13];
    const float* g2e = (const float*)d_in[14];
    const float* w0s = (const float*)d_in[15];
    const float* w01 = (const float*)d_in[16];
    const float* w02 = (const float*)d_in[17];
    const float* wr11 = (const float*)d_in[18];
    const float* wi11 = (const float*)d_in[19];
    const float* wr12 = (const float*)d_in[20];
    const float* wi12 = (const float*)d_in[21];
    const float* wr22 = (const float*)d_in[22];
    const float* wi22 = (const float*)d_in[23];
    const float* wp0 = (const float*)d_in[24];
    const float* bp0 = (const float*)d_in[25];
    const float* wp1 = (const float*)d_in[26];
    const float* wp2 = (const float*)d_in[27];
    const float* wenv = (const float*)d_in[28];
    const float* benv = (const float*)d_in[29];
    float* out = (float*)d_out;
    float* nrm = (float*)d_ws;                         // N*288 f32 = 11.52 MB (planar)
    ushort* pkw = (ushort*)((char*)d_ws + (size_t)NRM_FLOATS * 4);  // 246 KB packed bf16 weights

    pack_k<<<(PKTOT + 255) / 256, 256, 0, stream>>>(w0s, w01, w02, wr11, wi11, wr12, wi12,
                                                    wr22, wi22, wenv, wp0, wp1, wp2, pkw);
    node_norm_k<<<(NN + 3) / 4, 256, 0, stream>>>(nf, g0n, b0n, g1n, g2n, nrm, out);
    edge_k<<<EE / EPB, 256, 0, stream>>>(latents, efe, evec, eidx, act,
        g0e, b0e, g1e, g2e, pkw, bp0, benv, nrm, out);
}

// Round 6
// 392.528 us; speedup vs baseline: 1.5030x; 1.5030x over previous
//
#include <hip/hip_runtime.h>
#include <math.h>

#define NN 10000
#define EE 100000
#define EPB 8           // edges per block
#define AST 1000        // sA row stride (ushorts): 2000B rows -> conflict-free row banks
#define YSTH 456        // sY row stride (ushorts, bf16)
#define PST 40          // proj area row stride (ushorts / floats)

// staged-input segment offsets within an sA row (ushort index)
#define SEG0 0
#define SEGP1 288
#define SEGM1 480
#define SEGP2 672
#define SEGM2 768
#define SEGL 864

// sY per-edge layout (bf16)
#define Y0o   0
#define Y10o  96
#define Y20o  128
#define Y1Po  160
#define Y1Mo  192
#define Y2P1o 224
#define Y2M1o 256
#define Y2P2o 288
#define Y2M2o 320
#define WENVo 352

// packed-weight region offsets (ushort index)
#define PK1 0
#define PK2 46080
#define PK3 95232
#define PK4 107520
#define PKP 119808
#define PKTOT 122880

// workspace layout (bytes)
#define WS_NRM 0
#define WS_PK  11520000
#define WS_CNT 11765760
#define WS_OFF 11831296
#define WS_CUR 11896832
#define WS_EL  11962368
#define WS_MSG 12486656
#define WS_REQ (WS_MSG + (size_t)EE*288*2)

#define SQ3F  1.7320508075688772f
#define S0F   0.05892556509887896f
#define S1F   0.07216878364870323f
#define S2F   0.10206207261596575f
#define SEF   0.08838834764831845f
#define SCF   0.17677669529663687f
#define COLDF 0.8944271909999159f
#define COEFF 0.1414213562373095f

typedef __attribute__((ext_vector_type(8))) short bf16x8;
typedef __attribute__((ext_vector_type(4))) float f32x4;

__device__ __forceinline__ ushort f2bf(float f) {
    union { float f; unsigned u; } v; v.f = f;
    unsigned r = v.u + 0x7fff + ((v.u >> 16) & 1);
    return (ushort)(r >> 16);
}
__device__ __forceinline__ float bf2f(ushort u) {
    union { unsigned u; float f; } v; v.u = (unsigned)u << 16; return v.f;
}

__device__ __forceinline__ int planar(int k) {
    if (k < 32) return k;
    if (k < 128) { int c = (k - 32) / 3, m = (k - 32) % 3; return 32 + 32*m + c; }
    int c = (k - 128) / 5, m = (k - 128) % 5; return 128 + 32*m + c;
}

// ---------------- weight pre-pack ----------------
__global__ __launch_bounds__(256) void pack_k(
    const float* __restrict__ w0s, const float* __restrict__ w01, const float* __restrict__ w02,
    const float* __restrict__ wr11, const float* __restrict__ wi11,
    const float* __restrict__ wr12, const float* __restrict__ wi12,
    const float* __restrict__ wr22, const float* __restrict__ wi22,
    const float* __restrict__ wenv,
    const float* __restrict__ wp0, const float* __restrict__ wp1, const float* __restrict__ wp2,
    ushort* __restrict__ pk)
{
    int i = blockIdx.x * 256 + threadIdx.x;
    if (i >= PKTOT) return;
    float val;
    if (i < PK2) {
        int idx = i - PK1;
        int tile = idx / 4608, rem = idx % 4608;
        int chunk = rem / 512, rem2 = rem % 512;
        int lane = rem2 / 8, j = rem2 % 8;
        int col = tile * 16 + (lane & 15);
        int k = chunk * 32 + (lane >> 4) * 8 + j;
        if (col < 96)       val = w0s[col * 288 + k];
        else if (col < 128) val = w01[(col - 96) * 288 + k];
        else                val = w02[(col - 128) * 288 + k];
    } else if (i < PK3) {
        int idx = i - PK2;
        int tile = idx / 6144, rem = idx % 6144;
        int chunk = rem / 512, rem2 = rem % 512;
        int lane = rem2 / 8, j = rem2 % 8;
        int col = tile * 16 + (lane & 15);
        int k = chunk * 32 + (lane >> 4) * 8 + j;
        int grp = col >> 5, c = col & 31;
        if (k < 192) {
            val = (grp == 0) ? wr11[c*192 + k] : (grp == 1) ? wi11[c*192 + k]
                : (grp == 2) ? wr12[c*192 + k] : wi12[c*192 + k];
        } else {
            int kk = k - 192;
            val = (grp == 0) ? -wi11[c*192 + kk] : (grp == 1) ? wr11[c*192 + kk]
                : (grp == 2) ? -wi12[c*192 + kk] : wr12[c*192 + kk];
        }
    } else if (i < PK4) {
        int idx = i - PK3;
        int tile = idx / 3072, rem = idx % 3072;
        int chunk = rem / 512, rem2 = rem % 512;
        int lane = rem2 / 8, j = rem2 % 8;
        int col = tile * 16 + (lane & 15);
        int k = chunk * 32 + (lane >> 4) * 8 + j;
        int grp = col >> 5, c = col & 31;
        if (k < 96) val = grp ? wi22[c*96 + k] : wr22[c*96 + k];
        else        val = grp ? wr22[c*96 + k - 96] : -wi22[c*96 + k - 96];
    } else if (i < PKP) {
        int idx = i - PK4;
        int tile = idx / 2048, rem = idx % 2048;
        int chunk = rem / 512, rem2 = rem % 512;
        int lane = rem2 / 8, j = rem2 % 8;
        int col = tile * 16 + (lane & 15);
        int k = chunk * 32 + (lane >> 4) * 8 + j;
        val = wenv[col * 128 + k];
    } else {
        int idx = i - PKP;
        int wpi = idx / 1024, rem = idx % 1024;
        int ct = rem / 512, rem2 = rem % 512;
        int lane = rem2 / 8, j = rem2 % 8;
        int col = ct * 16 + (lane & 15);
        int k = (lane >> 4) * 8 + j;
        const float* w = (wpi == 0) ? wp0 : (wpi == 1) ? wp1 : wp2;
        val = w[col * 32 + k];
    }
    pk[i] = f2bf(val);
}

// ---------------- node SLN -> planar nrm (out write only in fallback) ----------------
__global__ __launch_bounds__(256) void node_norm_k(
    const float* __restrict__ nf,
    const float* __restrict__ g0, const float* __restrict__ b0,
    const float* __restrict__ g1, const float* __restrict__ g2,
    float* __restrict__ nrm, float* __restrict__ out)
{
    int row = blockIdx.x * 4 + (threadIdx.x >> 6);
    if (row >= NN) return;
    int lane = threadIdx.x & 63;
    const float* r = nf + (size_t)row * 288;
    float v0 = r[lane];
    float v1 = r[lane + 64];
    float v2 = r[lane + 128];
    float v3 = r[lane + 192];
    float v4 = (lane < 32) ? r[lane + 256] : 0.f;
    float s0 = 0.f, s0q = 0.f, q1 = 0.f, q2 = 0.f;
    if (lane < 32) { s0 = v0; s0q = v0*v0; } else { q1 = v0*v0; }
    q1 += v1*v1;
    q2 += v2*v2 + v3*v3 + v4*v4;
#pragma unroll
    for (int m = 1; m < 64; m <<= 1) {
        s0  += __shfl_xor(s0, m);
        s0q += __shfl_xor(s0q, m);
        q1  += __shfl_xor(q1, m);
        q2  += __shfl_xor(q2, m);
    }
    float mu  = s0 * (1.f/32.f);
    float var = s0q * (1.f/32.f) - mu*mu;
    float rs0 = rsqrtf(var + 1e-8f);
    float rv  = 0.5f * (q1 * (1.f/96.f) + q2 * (1.f/160.f));
    float rs  = rsqrtf(rv + 1e-8f);
    float* nr = nrm + (size_t)row * 288;
    {
        float res;
        if (lane < 32) res = (v0 - mu) * rs0 * g0[lane] + b0[lane];
        else { int c = (lane - 32) / 3; res = v0 * rs * g1[c]; }
        nr[planar(lane)] = res;
    }
    { int k = lane + 64;  int c = (k - 32) / 3;  nr[planar(k)] = v1 * rs * g1[c]; }
    { int k = lane + 128; int c = (k - 128) / 5; nr[planar(k)] = v2 * rs * g2[c]; }
    { int k = lane + 192; int c = (k - 128) / 5; nr[planar(k)] = v3 * rs * g2[c]; }
    if (lane < 32) { int k = lane + 256; int c = (k - 128) / 5; nr[planar(k)] = v4 * rs * g2[c]; }
    if (out) {
        float* orow = out + (size_t)row * 288;
        orow[lane]       = COLDF * v0;
        orow[lane + 64]  = COLDF * v1;
        orow[lane + 128] = COLDF * v2;
        orow[lane + 192] = COLDF * v3;
        if (lane < 32) orow[lane + 256] = COLDF * v4;
    }
}

// ---------------- CSR build ----------------
__global__ __launch_bounds__(256) void zero_k(int* __restrict__ counts) {
    int i = blockIdx.x * 256 + threadIdx.x;
    if (i < NN) counts[i] = 0;
}
__global__ __launch_bounds__(256) void hist_k(
    const int* __restrict__ eidx, const int* __restrict__ act, int* __restrict__ counts) {
    int e = blockIdx.x * 256 + threadIdx.x;
    if (e >= EE) return;
    atomicAdd(&counts[eidx[act[e]]], 1);
}
__global__ __launch_bounds__(256) void scan_k(
    const int* __restrict__ counts, int* __restrict__ offs, int* __restrict__ curs) {
    __shared__ int sbuf[256];
    __shared__ int scarry;
    if (threadIdx.x == 0) scarry = 0;
    __syncthreads();
    for (int base = 0; base < NN; base += 256) {
        int i = base + threadIdx.x;
        int v = (i < NN) ? counts[i] : 0;
        sbuf[threadIdx.x] = v;
        __syncthreads();
        for (int off = 1; off < 256; off <<= 1) {
            int t = (threadIdx.x >= off) ? sbuf[threadIdx.x - off] : 0;
            __syncthreads();
            sbuf[threadIdx.x] += t;
            __syncthreads();
        }
        int excl = sbuf[threadIdx.x] - v;
        if (i < NN) { int o = scarry + excl; offs[i] = o; curs[i] = o; }
        __syncthreads();
        if (threadIdx.x == 255) scarry += sbuf[255];
        __syncthreads();
    }
}
__global__ __launch_bounds__(256) void scatter_k(
    const int* __restrict__ eidx, const int* __restrict__ act,
    int* __restrict__ curs, int* __restrict__ elist) {
    int e = blockIdx.x * 256 + threadIdx.x;
    if (e >= EE) return;
    int pos = atomicAdd(&curs[eidx[act[e]]], 1);
    elist[pos] = e;
}

// ---------------- gather: out = c_old*nf + c_new * sum(msg) ----------------
__global__ __launch_bounds__(256) void gather_k(
    const ushort* __restrict__ msg, const int* __restrict__ offs,
    const int* __restrict__ counts, const int* __restrict__ elist,
    const float* __restrict__ nf, float* __restrict__ out)
{
    int node = blockIdx.x * 4 + (threadIdx.x >> 6);
    if (node >= NN) return;
    int lane = threadIdx.x & 63;
    int start = offs[node], cnt = counts[node];
    float a0 = 0.f, a1 = 0.f, a2 = 0.f, a3 = 0.f, a4 = 0.f;
    for (int i = 0; i < cnt; ++i) {
        int e = elist[start + i];
        const ushort* mr = msg + (size_t)e * 288;
        a0 += bf2f(mr[lane]);
        a1 += bf2f(mr[lane + 64]);
        a2 += bf2f(mr[lane + 128]);
        a3 += bf2f(mr[lane + 192]);
        if (lane < 32) a4 += bf2f(mr[lane + 256]);
    }
    const float* r = nf + (size_t)node * 288;
    float* o = out + (size_t)node * 288;
    o[lane]       = COLDF * r[lane]       + COEFF * a0;
    o[lane + 64]  = COLDF * r[lane + 64]  + COEFF * a1;
    o[lane + 128] = COLDF * r[lane + 128] + COEFF * a2;
    o[lane + 192] = COLDF * r[lane + 192] + COEFF * a3;
    if (lane < 32) o[lane + 256] = COLDF * r[lane + 256] + COEFF * a4;
}

// ---------------- fused edge kernel: 256 threads / 8 edges ----------------
__global__ __launch_bounds__(256, 6) void edge_k(
    const float* __restrict__ lat, const float* __restrict__ ef,
    const float* __restrict__ evec,
    const int* __restrict__ eidx, const int* __restrict__ act,
    const float* __restrict__ g0e, const float* __restrict__ b0e,
    const float* __restrict__ g1e, const float* __restrict__ g2e,
    const ushort* __restrict__ pk,
    const float* __restrict__ bp0, const float* __restrict__ benv,
    const float* __restrict__ nrm, ushort* __restrict__ msg, float* __restrict__ out)
{
    __shared__ __align__(16) ushort sA[EPB * AST];   // staged A; reused as proj-A then sP (f32)
    __shared__ __align__(16) ushort sY[EPB * YSTH];
    __shared__ float sD1[EPB][12];
    __shared__ float sD2[EPB][28];
    __shared__ int sAe[EPB], sCtr[EPB], sNbr[EPB];

    const int tid = threadIdx.x;
    const int wv = tid >> 6, lane = tid & 63;

    if (tid < EPB) {
        int ae = act[blockIdx.x * EPB + tid];
        sAe[tid] = ae;
        sCtr[tid] = eidx[ae];
        sNbr[tid] = eidx[EE + ae];
    }
    __syncthreads();

    // ---------------- prep: wave per edge, 2 iterations ----------------
    for (int it = 0; it < 2; ++it) {
        const int e = it * 4 + wv;
        const int ae = sAe[e];
        const int ctr = sCtr[e], nbr = sNbr[e];
        ushort* row = sA + e * AST;
        ushort* sEb = sY + e * YSTH;
        const float* efr = ef + (size_t)ae * 288;

        float ev0 = efr[lane];
        float ev1 = efr[lane + 64];
        float ev2 = efr[lane + 128];
        float ev3 = efr[lane + 192];
        float ev4 = (lane < 32) ? efr[lane + 256] : 0.f;
        float s0 = 0.f, s0q = 0.f, q1 = 0.f, q2 = 0.f;
        if (lane < 32) { s0 = ev0; s0q = ev0*ev0; } else { q1 = ev0*ev0; }
        q1 += ev1*ev1;
        q2 += ev2*ev2 + ev3*ev3 + ev4*ev4;
#pragma unroll
        for (int m = 1; m < 64; m <<= 1) {
            s0  += __shfl_xor(s0, m);
            s0q += __shfl_xor(s0q, m);
            q1  += __shfl_xor(q1, m);
            q2  += __shfl_xor(q2, m);
        }
        float mu  = s0 * (1.f/32.f);
        float rs0 = rsqrtf(s0q*(1.f/32.f) - mu*mu + 1e-8f);
        float rs  = rsqrtf(0.5f*(q1*(1.f/96.f) + q2*(1.f/160.f)) + 1e-8f);

        if (lane >= 32) { int c = (lane-32)/3, m = (lane-32)%3; sEb[32 + 32*m + c] = f2bf(ev0 * rs * g1e[c]); }
        { int k = lane+64;  int c = (k-32)/3,  m = (k-32)%3;  sEb[32 + 32*m + c]  = f2bf(ev1 * rs * g1e[c]); }
        { int k = lane+128; int c = (k-128)/5, m = (k-128)%5; sEb[128 + 32*m + c] = f2bf(ev2 * rs * g2e[c]); }
        { int k = lane+192; int c = (k-128)/5, m = (k-128)%5; sEb[128 + 32*m + c] = f2bf(ev3 * rs * g2e[c]); }
        if (lane < 32) { int k = lane+256; int c = (k-128)/5, m = (k-128)%5; sEb[128 + 32*m + c] = f2bf(ev4 * rs * g2e[c]); }

        if (lane < 32) {
            row[SEG0 + 32 + lane] = f2bf((ev0 - mu) * rs0 * g0e[lane] + b0e[lane]);
            row[SEG0 + lane]      = f2bf(nrm[(size_t)ctr*288 + lane]);
            row[SEG0 + 64 + lane] = f2bf(nrm[(size_t)nbr*288 + lane]);
        }
        {
            const float* lr = lat + (size_t)ae * 128;
            row[SEGL + lane]      = f2bf(lr[lane]);
            row[SEGL + 64 + lane] = f2bf(lr[lane + 64]);
        }

        float vx = evec[3*ae], vy = evec[3*ae+1], vz = evec[3*ae+2];
        float nnv = fmaxf(sqrtf(vx*vx + vy*vy + vz*vz), 1e-9f);
        float nx = vx/nnv, ny = vy/nnv, nz = vz/nnv;
        float ax, az;
        if (fabsf(nx) < 0.9f) { ax = 1.f; az = 0.f; } else { ax = 0.f; az = 1.f; }
        float adn = ax*nx + az*nz;
        float ux = ax - adn*nx, uy = -adn*ny, uz = az - adn*nz;
        float un = fmaxf(sqrtf(ux*ux + uy*uy + uz*uz), 1e-9f);
        ux /= un; uy /= un; uz /= un;
        float wx = uy*nz - uz*ny, wy = uz*nx - ux*nz, wz = ux*ny - uy*nx;

        float d2[5][5];
        d2[0][0] = wz*ux + uz*wx;  d2[0][1] = wx*uy + ux*wy;  d2[0][2] = SQ3F*wy*uy;
        d2[0][3] = wy*uz + uy*wz;  d2[0][4] = wz*uz - wx*ux;
        d2[1][0] = uz*nx + nz*ux;  d2[1][1] = ux*ny + nx*uy;  d2[1][2] = SQ3F*uy*ny;
        d2[1][3] = uy*nz + ny*uz;  d2[1][4] = uz*nz - ux*nx;
        d2[2][0] = SQ3F*nz*nx;     d2[2][1] = SQ3F*nx*ny;     d2[2][2] = 1.5f*ny*ny - 0.5f;
        d2[2][3] = SQ3F*ny*nz;     d2[2][4] = 0.5f*SQ3F*(nz*nz - nx*nx);
        d2[3][0] = nz*wx + wz*nx;  d2[3][1] = nx*wy + wx*ny;  d2[3][2] = SQ3F*ny*wy;
        d2[3][3] = ny*wz + wy*nz;  d2[3][4] = nz*wz - nx*wx;
        d2[4][0] = wz*wx - uz*ux;  d2[4][1] = wx*wy - ux*uy;  d2[4][2] = 0.5f*SQ3F*(wy*wy - uy*uy);
        d2[4][3] = wy*wz - uy*uz;  d2[4][4] = 0.5f*(wz*wz - uz*uz - wx*wx + ux*ux);

        if (lane == 0) {
            sD1[e][0] = ux; sD1[e][1] = uy; sD1[e][2] = uz;
            sD1[e][3] = nx; sD1[e][4] = ny; sD1[e][5] = nz;
            sD1[e][6] = wx; sD1[e][7] = wy; sD1[e][8] = wz;
#pragma unroll
            for (int n = 0; n < 5; ++n)
#pragma unroll
                for (int m = 0; m < 5; ++m) sD2[e][5*n + m] = d2[n][m];
        }

        asm volatile("s_waitcnt lgkmcnt(0)" ::: "memory");

#pragma unroll
        for (int half = 0; half < 2; ++half) {
            const int cc = lane + 64*half;
            if (cc < 96) {
                float x1v[3], x2v[5];
                if (cc < 32) {
                    const float* b = nrm + (size_t)ctr * 288;
#pragma unroll
                    for (int m = 0; m < 3; ++m) x1v[m] = b[32 + 32*m + cc];
#pragma unroll
                    for (int m = 0; m < 5; ++m) x2v[m] = b[128 + 32*m + cc];
                } else if (cc < 64) {
                    const int c = cc - 32;
#pragma unroll
                    for (int m = 0; m < 3; ++m) x1v[m] = bf2f(sEb[32 + 32*m + c]);
#pragma unroll
                    for (int m = 0; m < 5; ++m) x2v[m] = bf2f(sEb[128 + 32*m + c]);
                } else {
                    const float* b = nrm + (size_t)nbr * 288;
                    const int c = cc - 64;
#pragma unroll
                    for (int m = 0; m < 3; ++m) x1v[m] = b[32 + 32*m + c];
#pragma unroll
                    for (int m = 0; m < 5; ++m) x2v[m] = b[128 + 32*m + c];
                }
                float r0 = ux*x1v[0] + uy*x1v[1] + uz*x1v[2];
                float r1 = nx*x1v[0] + ny*x1v[1] + nz*x1v[2];
                float r2 = wx*x1v[0] + wy*x1v[1] + wz*x1v[2];
                float t[5];
#pragma unroll
                for (int m = 0; m < 5; ++m)
                    t[m] = d2[m][0]*x2v[0] + d2[m][1]*x2v[1] + d2[m][2]*x2v[2]
                         + d2[m][3]*x2v[3] + d2[m][4]*x2v[4];
                row[SEG0 + 96  + cc] = f2bf(r1);
                row[SEG0 + 192 + cc] = f2bf(t[2]);
                row[SEGP1 + cc]      = f2bf(r2);
                row[SEGP1 + 96 + cc] = f2bf(t[3]);
                row[SEGM1 + cc]      = f2bf(r0);
                row[SEGM1 + 96 + cc] = f2bf(t[1]);
                row[SEGP2 + cc]      = f2bf(t[4]);
                row[SEGM2 + cc]      = f2bf(t[0]);
            }
        }
    }
    __syncthreads();

    // ---------------- MFMA GEMM phase ----------------
    for (int t = wv; t < 28; t += 4) {
        int kbase, nch, yoff, pbase; float scale;
        if (t < 10)      { kbase = SEG0;  nch = 9;  yoff = t*16;          scale = S0F; pbase = PK1 + t*9*512; }
        else if (t < 18) { kbase = SEGP1; nch = 12; yoff = 160+(t-10)*16; scale = S1F; pbase = PK2 + (t-10)*12*512; }
        else if (t < 22) { kbase = SEGP2; nch = 6;  yoff = 288+(t-18)*16; scale = S2F; pbase = PK3 + (t-18)*6*512; }
        else             { kbase = SEGL;  nch = 4;  yoff = 352+(t-22)*16; scale = SEF; pbase = PK4 + (t-22)*4*512; }
        f32x4 acc = {0.f, 0.f, 0.f, 0.f};
        const ushort* pa = sA + (lane & 7) * AST + kbase + (lane >> 4) * 8;
        const ushort* pb = pk + pbase + lane * 8;
        for (int ch = 0; ch < nch; ++ch) {
            bf16x8 a = *reinterpret_cast<const bf16x8*>(pa + ch * 32);
            bf16x8 b = *reinterpret_cast<const bf16x8*>(pb + ch * 512);
            acc = __builtin_amdgcn_mfma_f32_16x16x32_bf16(a, b, acc, 0, 0, 0);
        }
        const int col = yoff + (lane & 15);
        const int r0 = (lane >> 4) * 4;
        if (r0 < EPB) {
            float bv = (t >= 22) ? benv[col - 352] : 0.f;
#pragma unroll
            for (int j = 0; j < 4; ++j)
                sY[(r0 + j) * YSTH + col] = f2bf(acc[j] * scale + bv);
        }
    }
    __syncthreads();

    // ---------------- stage 2a: gates, gated n-frame A-matrix (rows x 32, stride PST) ----------------
    const int e2 = tid & 7, c = tid >> 3;
    const ushort* yrow = sY + e2 * YSTH;
    {
        float y0v = bf2f(yrow[Y0o + c]);
        float scv = y0v / (1.f + expf(-y0v));
        float gg1 = 1.f / (1.f + expf(-bf2f(yrow[Y0o + 32 + c])));
        float gg2 = 1.f / (1.f + expf(-bf2f(yrow[Y0o + 64 + c])));
        sA[(0  + e2)*PST + c] = f2bf(scv);
        sA[(16 + e2)*PST + c] = f2bf(bf2f(yrow[Y1Mo  + c]) * gg1);
        sA[(24 + e2)*PST + c] = f2bf(bf2f(yrow[Y10o  + c]) * gg1);
        sA[(32 + e2)*PST + c] = f2bf(bf2f(yrow[Y1Po  + c]) * gg1);
        sA[(48 + e2)*PST + c] = f2bf(bf2f(yrow[Y2M2o + c]) * gg2);
        sA[(56 + e2)*PST + c] = f2bf(bf2f(yrow[Y2M1o + c]) * gg2);
        sA[(64 + e2)*PST + c] = f2bf(bf2f(yrow[Y20o  + c]) * gg2);
        sA[(72 + e2)*PST + c] = f2bf(bf2f(yrow[Y2P1o + c]) * gg2);
        sA[(80 + e2)*PST + c] = f2bf(bf2f(yrow[Y2P2o + c]) * gg2);
    }
    __syncthreads();

    // ---------------- proj MFMA: 12 tiles across 4 waves ----------------
    f32x4 pacc[3];
#pragma unroll
    for (int q = 0; q < 3; ++q) {
        const int tt = wv * 3 + q;
        const int rt = tt >> 1, ct = tt & 1;
        const int wpi = (rt == 0) ? 0 : (rt < 3) ? 1 : 2;
        bf16x8 a = *reinterpret_cast<const bf16x8*>(sA + (rt*16 + (lane & 15))*PST + (lane >> 4)*8);
        bf16x8 b = *reinterpret_cast<const bf16x8*>(pk + PKP + wpi*1024 + ct*512 + lane*8);
        f32x4 z = {0.f, 0.f, 0.f, 0.f};
        pacc[q] = __builtin_amdgcn_mfma_f32_16x16x32_bf16(a, b, z, 0, 0, 0);
    }
    __syncthreads();

    float* sPf = reinterpret_cast<float*>(sA);
#pragma unroll
    for (int q = 0; q < 3; ++q) {
        const int tt = wv * 3 + q;
        const int rt = tt >> 1, ct = tt & 1;
        const int col = ct*16 + (lane & 15);
#pragma unroll
        for (int j = 0; j < 4; ++j) {
            const int rw = rt*16 + (lane >> 4)*4 + j;
            const bool used = (rw < 8) || (rw >= 16 && rw < 40) || (rw >= 48 && rw < 88);
            if (used) sPf[rw*PST + col] = pacc[q][j];
        }
    }
    __syncthreads();

    // ---------------- stage 2b: rotate-back + env gate -> msg write (or atomic fallback) ----------------
    const int d = c;
    {
        float wv0g = bf2f(yrow[WENVo + d]);
        float m0v = (sPf[e2*PST + d] * SCF + bp0[d]) * wv0g;

        float p1v[3], p2v[5];
#pragma unroll
        for (int m = 0; m < 3; ++m) p1v[m] = sPf[(16 + 8*m + e2)*PST + d];
#pragma unroll
        for (int m = 0; m < 5; ++m) p2v[m] = sPf[(48 + 8*m + e2)*PST + d];

        float wv1g = bf2f(yrow[WENVo + 32 + d]) * SCF;
        float wv2g = bf2f(yrow[WENVo + 64 + d]) * SCF;

        float o1[3], o2[5];
#pragma unroll
        for (int mm = 0; mm < 3; ++mm)
            o1[mm] = (sD1[e2][mm]*p1v[0] + sD1[e2][3+mm]*p1v[1] + sD1[e2][6+mm]*p1v[2]) * wv1g;
#pragma unroll
        for (int mm = 0; mm < 5; ++mm)
            o2[mm] = (sD2[e2][mm]*p2v[0] + sD2[e2][5+mm]*p2v[1] + sD2[e2][10+mm]*p2v[2]
                    + sD2[e2][15+mm]*p2v[3] + sD2[e2][20+mm]*p2v[4]) * wv2g;

        if (msg) {
            ushort* mr = msg + (size_t)(blockIdx.x * EPB + e2) * 288;
            mr[d] = f2bf(m0v);
#pragma unroll
            for (int mm = 0; mm < 3; ++mm) mr[32 + 3*d + mm] = f2bf(o1[mm]);
#pragma unroll
            for (int mm = 0; mm < 5; ++mm) mr[128 + 5*d + mm] = f2bf(o2[mm]);
        } else {
            float* ob = out + (size_t)sCtr[e2] * 288;
            atomicAdd(ob + d, COEFF * m0v);
#pragma unroll
            for (int mm = 0; mm < 3; ++mm) atomicAdd(ob + 32 + 3*d + mm, COEFF * o1[mm]);
#pragma unroll
            for (int mm = 0; mm < 5; ++mm) atomicAdd(ob + 128 + 5*d + mm, COEFF * o2[mm]);
        }
    }
}

extern "C" void kernel_launch(void* const* d_in, const int* in_sizes, int n_in,
                              void* d_out, int out_size, void* d_ws, size_t ws_size,
                              hipStream_t stream)
{
    const float* latents = (const float*)d_in[0];
    const float* nf      = (const float*)d_in[1];
    const float* efe     = (const float*)d_in[2];
    const float* evec    = (const float*)d_in[3];
    const int*   eidx    = (const int*)d_in[5];
    const int*   act     = (const int*)d_in[6];
    const float* g0n = (const float*)d_in[7];
    const float* b0n = (const float*)d_in[8];
    const float* g1n = (const float*)d_in[9];
    const float* g2n = (const float*)d_in[10];
    const float* g0e = (const float*)d_in[11];
    const float* b0e = (const float*)d_in[12];
    const float* g1e = (const float*)d_in[13];
    const float* g2e = (const float*)d_in[14];
    const float* w0s = (const float*)d_in[15];
    const float* w01 = (const float*)d_in[16];
    const float* w02 = (const float*)d_in[17];
    const float* wr11 = (const float*)d_in[18];
    const float* wi11 = (const float*)d_in[19];
    const float* wr12 = (const float*)d_in[20];
    const float* wi12 = (const float*)d_in[21];
    const float* wr22 = (const float*)d_in[22];
    const float* wi22 = (const float*)d_in[23];
    const float* wp0 = (const float*)d_in[24];
    const float* bp0 = (const float*)d_in[25];
    const float* wp1 = (const float*)d_in[26];
    const float* wp2 = (const float*)d_in[27];
    const float* wenv = (const float*)d_in[28];
    const float* benv = (const float*)d_in[29];
    float* out = (float*)d_out;

    char* ws = (char*)d_ws;
    float* nrm  = (float*)(ws + WS_NRM);
    ushort* pkw = (ushort*)(ws + WS_PK);
    const bool use_msg = (ws_size >= WS_REQ);
    int* counts = (int*)(ws + WS_CNT);
    int* offs   = (int*)(ws + WS_OFF);
    int* curs   = (int*)(ws + WS_CUR);
    int* elist  = (int*)(ws + WS_EL);
    ushort* msg = (ushort*)(ws + WS_MSG);

    pack_k<<<(PKTOT + 255) / 256, 256, 0, stream>>>(w0s, w01, w02, wr11, wi11, wr12, wi12,
                                                    wr22, wi22, wenv, wp0, wp1, wp2, pkw);
    node_norm_k<<<(NN + 3) / 4, 256, 0, stream>>>(nf, g0n, b0n, g1n, g2n, nrm,
                                                  use_msg ? nullptr : out);
    if (use_msg) {
        zero_k<<<(NN + 255) / 256, 256, 0, stream>>>(counts);
        hist_k<<<(EE + 255) / 256, 256, 0, stream>>>(eidx, act, counts);
        scan_k<<<1, 256, 0, stream>>>(counts, offs, curs);
        scatter_k<<<(EE + 255) / 256, 256, 0, stream>>>(eidx, act, curs, elist);
    }
    edge_k<<<EE / EPB, 256, 0, stream>>>(latents, efe, evec, eidx, act,
        g0e, b0e, g1e, g2e, pkw, bp0, benv, nrm, use_msg ? msg : nullptr, out);
    if (use_msg) {
        gather_k<<<(NN + 3) / 4, 256, 0, stream>>>(msg, offs, counts, elist, nf, out);
    }
}

// Round 7
// 313.287 us; speedup vs baseline: 1.8832x; 1.2529x over previous
//
#include <hip/hip_runtime.h>
#include <math.h>

#define NN 10000
#define EE 100000
#define EPB 16          // edges per block
#define AST 1000        // sA row stride (ushorts)
#define YSTH 456        // sY row stride (ushorts, bf16)
#define PST 40          // proj area row stride (ushorts / floats), 80B rows (16B aligned)

// staged-input segment offsets within an sA row (ushort index)
#define SEG0 0
#define SEGP1 288
#define SEGM1 480
#define SEGP2 672
#define SEGM2 768
#define SEGL 864

// sY per-edge layout (bf16)
#define Y0o   0
#define Y10o  96
#define Y20o  128
#define Y1Po  160
#define Y1Mo  192
#define Y2P1o 224
#define Y2M1o 256
#define Y2P2o 288
#define Y2M2o 320
#define WENVo 352

// packed-weight region offsets (ushort index)
#define PK1 0
#define PK2 46080
#define PK3 95232
#define PK4 107520
#define PKP 119808
#define PKTOT 122880

// workspace layout (bytes)
#define WS_NRM 0
#define WS_PK  11520000
#define WS_CNT 11765760
#define WS_OFF 11831296
#define WS_CUR 11896832
#define WS_EL  11962368
#define WS_MSG 12486656
#define WS_REQ (WS_MSG + (size_t)EE*288*2)

#define SQ3F  1.7320508075688772f
#define S0F   0.05892556509887896f
#define S1F   0.07216878364870323f
#define S2F   0.10206207261596575f
#define SEF   0.08838834764831845f
#define SCF   0.17677669529663687f
#define COLDF 0.8944271909999159f
#define COEFF 0.1414213562373095f

typedef __attribute__((ext_vector_type(8))) short bf16x8;
typedef __attribute__((ext_vector_type(4))) float f32x4;

__device__ __forceinline__ ushort f2bf(float f) {
    union { float f; unsigned u; } v; v.f = f;
    unsigned r = v.u + 0x7fff + ((v.u >> 16) & 1);
    return (ushort)(r >> 16);
}
__device__ __forceinline__ float bf2f(ushort u) {
    union { unsigned u; float f; } v; v.u = (unsigned)u << 16; return v.f;
}

__device__ __forceinline__ int planar(int k) {
    if (k < 32) return k;
    if (k < 128) { int c = (k - 32) / 3, m = (k - 32) % 3; return 32 + 32*m + c; }
    int c = (k - 128) / 5, m = (k - 128) % 5; return 128 + 32*m + c;
}

// ---------------- weight pre-pack ----------------
__global__ __launch_bounds__(256) void pack_k(
    const float* __restrict__ w0s, const float* __restrict__ w01, const float* __restrict__ w02,
    const float* __restrict__ wr11, const float* __restrict__ wi11,
    const float* __restrict__ wr12, const float* __restrict__ wi12,
    const float* __restrict__ wr22, const float* __restrict__ wi22,
    const float* __restrict__ wenv,
    const float* __restrict__ wp0, const float* __restrict__ wp1, const float* __restrict__ wp2,
    ushort* __restrict__ pk)
{
    int i = blockIdx.x * 256 + threadIdx.x;
    if (i >= PKTOT) return;
    float val;
    if (i < PK2) {
        int idx = i - PK1;
        int tile = idx / 4608, rem = idx % 4608;
        int chunk = rem / 512, rem2 = rem % 512;
        int lane = rem2 / 8, j = rem2 % 8;
        int col = tile * 16 + (lane & 15);
        int k = chunk * 32 + (lane >> 4) * 8 + j;
        if (col < 96)       val = w0s[col * 288 + k];
        else if (col < 128) val = w01[(col - 96) * 288 + k];
        else                val = w02[(col - 128) * 288 + k];
    } else if (i < PK3) {
        int idx = i - PK2;
        int tile = idx / 6144, rem = idx % 6144;
        int chunk = rem / 512, rem2 = rem % 512;
        int lane = rem2 / 8, j = rem2 % 8;
        int col = tile * 16 + (lane & 15);
        int k = chunk * 32 + (lane >> 4) * 8 + j;
        int grp = col >> 5, c = col & 31;
        if (k < 192) {
            val = (grp == 0) ? wr11[c*192 + k] : (grp == 1) ? wi11[c*192 + k]
                : (grp == 2) ? wr12[c*192 + k] : wi12[c*192 + k];
        } else {
            int kk = k - 192;
            val = (grp == 0) ? -wi11[c*192 + kk] : (grp == 1) ? wr11[c*192 + kk]
                : (grp == 2) ? -wi12[c*192 + kk] : wr12[c*192 + kk];
        }
    } else if (i < PK4) {
        int idx = i - PK3;
        int tile = idx / 3072, rem = idx % 3072;
        int chunk = rem / 512, rem2 = rem % 512;
        int lane = rem2 / 8, j = rem2 % 8;
        int col = tile * 16 + (lane & 15);
        int k = chunk * 32 + (lane >> 4) * 8 + j;
        int grp = col >> 5, c = col & 31;
        if (k < 96) val = grp ? wi22[c*96 + k] : wr22[c*96 + k];
        else        val = grp ? wr22[c*96 + k - 96] : -wi22[c*96 + k - 96];
    } else if (i < PKP) {
        int idx = i - PK4;
        int tile = idx / 2048, rem = idx % 2048;
        int chunk = rem / 512, rem2 = rem % 512;
        int lane = rem2 / 8, j = rem2 % 8;
        int col = tile * 16 + (lane & 15);
        int k = chunk * 32 + (lane >> 4) * 8 + j;
        val = wenv[col * 128 + k];
    } else {
        int idx = i - PKP;
        int wpi = idx / 1024, rem = idx % 1024;
        int ct = rem / 512, rem2 = rem % 512;
        int lane = rem2 / 8, j = rem2 % 8;
        int col = ct * 16 + (lane & 15);
        int k = (lane >> 4) * 8 + j;
        const float* w = (wpi == 0) ? wp0 : (wpi == 1) ? wp1 : wp2;
        val = w[col * 32 + k];
    }
    pk[i] = f2bf(val);
}

// ---------------- node SLN -> planar nrm ----------------
__global__ __launch_bounds__(256) void node_norm_k(
    const float* __restrict__ nf,
    const float* __restrict__ g0, const float* __restrict__ b0,
    const float* __restrict__ g1, const float* __restrict__ g2,
    float* __restrict__ nrm, float* __restrict__ out)
{
    int row = blockIdx.x * 4 + (threadIdx.x >> 6);
    if (row >= NN) return;
    int lane = threadIdx.x & 63;
    const float* r = nf + (size_t)row * 288;
    float v0 = r[lane];
    float v1 = r[lane + 64];
    float v2 = r[lane + 128];
    float v3 = r[lane + 192];
    float v4 = (lane < 32) ? r[lane + 256] : 0.f;
    float s0 = 0.f, s0q = 0.f, q1 = 0.f, q2 = 0.f;
    if (lane < 32) { s0 = v0; s0q = v0*v0; } else { q1 = v0*v0; }
    q1 += v1*v1;
    q2 += v2*v2 + v3*v3 + v4*v4;
#pragma unroll
    for (int m = 1; m < 64; m <<= 1) {
        s0  += __shfl_xor(s0, m);
        s0q += __shfl_xor(s0q, m);
        q1  += __shfl_xor(q1, m);
        q2  += __shfl_xor(q2, m);
    }
    float mu  = s0 * (1.f/32.f);
    float var = s0q * (1.f/32.f) - mu*mu;
    float rs0 = rsqrtf(var + 1e-8f);
    float rv  = 0.5f * (q1 * (1.f/96.f) + q2 * (1.f/160.f));
    float rs  = rsqrtf(rv + 1e-8f);
    float* nr = nrm + (size_t)row * 288;
    {
        float res;
        if (lane < 32) res = (v0 - mu) * rs0 * g0[lane] + b0[lane];
        else { int c = (lane - 32) / 3; res = v0 * rs * g1[c]; }
        nr[planar(lane)] = res;
    }
    { int k = lane + 64;  int c = (k - 32) / 3;  nr[planar(k)] = v1 * rs * g1[c]; }
    { int k = lane + 128; int c = (k - 128) / 5; nr[planar(k)] = v2 * rs * g2[c]; }
    { int k = lane + 192; int c = (k - 128) / 5; nr[planar(k)] = v3 * rs * g2[c]; }
    if (lane < 32) { int k = lane + 256; int c = (k - 128) / 5; nr[planar(k)] = v4 * rs * g2[c]; }
    if (out) {
        float* orow = out + (size_t)row * 288;
        orow[lane]       = COLDF * v0;
        orow[lane + 64]  = COLDF * v1;
        orow[lane + 128] = COLDF * v2;
        orow[lane + 192] = COLDF * v3;
        if (lane < 32) orow[lane + 256] = COLDF * v4;
    }
}

// ---------------- CSR build ----------------
__global__ __launch_bounds__(256) void zero_k(int* __restrict__ counts) {
    int i = blockIdx.x * 256 + threadIdx.x;
    if (i < NN) counts[i] = 0;
}
__global__ __launch_bounds__(256) void hist_k(
    const int* __restrict__ eidx, const int* __restrict__ act, int* __restrict__ counts) {
    int e = blockIdx.x * 256 + threadIdx.x;
    if (e >= EE) return;
    atomicAdd(&counts[eidx[act[e]]], 1);
}
__global__ __launch_bounds__(256) void scan_k(
    const int* __restrict__ counts, int* __restrict__ offs, int* __restrict__ curs) {
    __shared__ int sbuf[256];
    __shared__ int scarry;
    if (threadIdx.x == 0) scarry = 0;
    __syncthreads();
    for (int base = 0; base < NN; base += 256) {
        int i = base + threadIdx.x;
        int v = (i < NN) ? counts[i] : 0;
        sbuf[threadIdx.x] = v;
        __syncthreads();
        for (int off = 1; off < 256; off <<= 1) {
            int t = (threadIdx.x >= off) ? sbuf[threadIdx.x - off] : 0;
            __syncthreads();
            sbuf[threadIdx.x] += t;
            __syncthreads();
        }
        int excl = sbuf[threadIdx.x] - v;
        if (i < NN) { int o = scarry + excl; offs[i] = o; curs[i] = o; }
        __syncthreads();
        if (threadIdx.x == 255) scarry += sbuf[255];
        __syncthreads();
    }
}
__global__ __launch_bounds__(256) void scatter_k(
    const int* __restrict__ eidx, const int* __restrict__ act,
    int* __restrict__ curs, int* __restrict__ elist) {
    int e = blockIdx.x * 256 + threadIdx.x;
    if (e >= EE) return;
    int pos = atomicAdd(&curs[eidx[act[e]]], 1);
    elist[pos] = e;
}

// ---------------- gather: out = c_old*nf + c_new * sum(msg) ----------------
__global__ __launch_bounds__(256) void gather_k(
    const ushort* __restrict__ msg, const int* __restrict__ offs,
    const int* __restrict__ counts, const int* __restrict__ elist,
    const float* __restrict__ nf, float* __restrict__ out)
{
    int node = blockIdx.x * 4 + (threadIdx.x >> 6);
    if (node >= NN) return;
    int lane = threadIdx.x & 63;
    int start = offs[node], cnt = counts[node];
    float a0 = 0.f, a1 = 0.f, a2 = 0.f, a3 = 0.f, a4 = 0.f;
    for (int i = 0; i < cnt; ++i) {
        int e = elist[start + i];
        const ushort* mr = msg + (size_t)e * 288;
        a0 += bf2f(mr[lane]);
        a1 += bf2f(mr[lane + 64]);
        a2 += bf2f(mr[lane + 128]);
        a3 += bf2f(mr[lane + 192]);
        if (lane < 32) a4 += bf2f(mr[lane + 256]);
    }
    const float* r = nf + (size_t)node * 288;
    float* o = out + (size_t)node * 288;
    o[lane]       = COLDF * r[lane]       + COEFF * a0;
    o[lane + 64]  = COLDF * r[lane + 64]  + COEFF * a1;
    o[lane + 128] = COLDF * r[lane + 128] + COEFF * a2;
    o[lane + 192] = COLDF * r[lane + 192] + COEFF * a3;
    if (lane < 32) o[lane + 256] = COLDF * r[lane + 256] + COEFF * a4;
}

// ---------------- fused edge kernel: 512 threads / 16 edges ----------------
__global__ __launch_bounds__(512, 6) void edge_k(
    const float* __restrict__ lat, const float* __restrict__ ef,
    const float* __restrict__ evec,
    const int* __restrict__ eidx, const int* __restrict__ act,
    const float* __restrict__ g0e, const float* __restrict__ b0e,
    const float* __restrict__ g1e, const float* __restrict__ g2e,
    const ushort* __restrict__ pk,
    const float* __restrict__ bp0, const float* __restrict__ benv,
    const float* __restrict__ nrm, ushort* __restrict__ msg, float* __restrict__ out)
{
    __shared__ __align__(16) ushort sA[EPB * AST];   // 32000B; reused proj-A then sP (f32)
    __shared__ __align__(16) ushort sY[EPB * YSTH];  // 14592B
    __shared__ float sD1[EPB][12];
    __shared__ float sD2[EPB][28];
    __shared__ int sAe[EPB], sCtr[EPB], sNbr[EPB];

    const int tid = threadIdx.x;
    const int wv = tid >> 6, lane = tid & 63;

    if (tid < EPB) {
        int ae = act[blockIdx.x * EPB + tid];
        sAe[tid] = ae;
        sCtr[tid] = eidx[ae];
        sNbr[tid] = eidx[EE + ae];
    }
    __syncthreads();

    // ---------------- prep part 1: wave per edge, 2 iterations ----------------
    for (int it = 0; it < 2; ++it) {
        const int e = it * 8 + wv;
        const int ae = sAe[e];
        const int ctr = sCtr[e], nbr = sNbr[e];
        ushort* row = sA + e * AST;
        ushort* sEb = sY + e * YSTH;
        const float* efr = ef + (size_t)ae * 288;

        float ev0 = efr[lane];
        float ev1 = efr[lane + 64];
        float ev2 = efr[lane + 128];
        float ev3 = efr[lane + 192];
        float ev4 = (lane < 32) ? efr[lane + 256] : 0.f;
        float s0 = 0.f, s0q = 0.f, q1 = 0.f, q2 = 0.f;
        if (lane < 32) { s0 = ev0; s0q = ev0*ev0; } else { q1 = ev0*ev0; }
        q1 += ev1*ev1;
        q2 += ev2*ev2 + ev3*ev3 + ev4*ev4;
#pragma unroll
        for (int m = 1; m < 64; m <<= 1) {
            s0  += __shfl_xor(s0, m);
            s0q += __shfl_xor(s0q, m);
            q1  += __shfl_xor(q1, m);
            q2  += __shfl_xor(q2, m);
        }
        float mu  = s0 * (1.f/32.f);
        float rs0 = rsqrtf(s0q*(1.f/32.f) - mu*mu + 1e-8f);
        float rs  = rsqrtf(0.5f*(q1*(1.f/96.f) + q2*(1.f/160.f)) + 1e-8f);

        if (lane >= 32) { int c = (lane-32)/3, m = (lane-32)%3; sEb[32 + 32*m + c] = f2bf(ev0 * rs * g1e[c]); }
        { int k = lane+64;  int c = (k-32)/3,  m = (k-32)%3;  sEb[32 + 32*m + c]  = f2bf(ev1 * rs * g1e[c]); }
        { int k = lane+128; int c = (k-128)/5, m = (k-128)%5; sEb[128 + 32*m + c] = f2bf(ev2 * rs * g2e[c]); }
        { int k = lane+192; int c = (k-128)/5, m = (k-128)%5; sEb[128 + 32*m + c] = f2bf(ev3 * rs * g2e[c]); }
        if (lane < 32) { int k = lane+256; int c = (k-128)/5, m = (k-128)%5; sEb[128 + 32*m + c] = f2bf(ev4 * rs * g2e[c]); }

        if (lane < 32) {
            row[SEG0 + 32 + lane] = f2bf((ev0 - mu) * rs0 * g0e[lane] + b0e[lane]);
            row[SEG0 + lane]      = f2bf(nrm[(size_t)ctr*288 + lane]);
            row[SEG0 + 64 + lane] = f2bf(nrm[(size_t)nbr*288 + lane]);
        }
        {
            const float* lr = lat + (size_t)ae * 128;
            row[SEGL + lane]      = f2bf(lr[lane]);
            row[SEGL + 64 + lane] = f2bf(lr[lane + 64]);
        }

        // local frame + analytic l=2 Wigner (redundant across lanes; lane 0 stores)
        float vx = evec[3*ae], vy = evec[3*ae+1], vz = evec[3*ae+2];
        float nnv = fmaxf(sqrtf(vx*vx + vy*vy + vz*vz), 1e-9f);
        float nx = vx/nnv, ny = vy/nnv, nz = vz/nnv;
        float ax, az;
        if (fabsf(nx) < 0.9f) { ax = 1.f; az = 0.f; } else { ax = 0.f; az = 1.f; }
        float adn = ax*nx + az*nz;
        float ux = ax - adn*nx, uy = -adn*ny, uz = az - adn*nz;
        float un = fmaxf(sqrtf(ux*ux + uy*uy + uz*uz), 1e-9f);
        ux /= un; uy /= un; uz /= un;
        float wx = uy*nz - uz*ny, wy = uz*nx - ux*nz, wz = ux*ny - uy*nx;

        if (lane == 0) {
            sD1[e][0] = ux; sD1[e][1] = uy; sD1[e][2] = uz;
            sD1[e][3] = nx; sD1[e][4] = ny; sD1[e][5] = nz;
            sD1[e][6] = wx; sD1[e][7] = wy; sD1[e][8] = wz;
            float d2[5][5];
            d2[0][0] = wz*ux + uz*wx;  d2[0][1] = wx*uy + ux*wy;  d2[0][2] = SQ3F*wy*uy;
            d2[0][3] = wy*uz + uy*wz;  d2[0][4] = wz*uz - wx*ux;
            d2[1][0] = uz*nx + nz*ux;  d2[1][1] = ux*ny + nx*uy;  d2[1][2] = SQ3F*uy*ny;
            d2[1][3] = uy*nz + ny*uz;  d2[1][4] = uz*nz - ux*nx;
            d2[2][0] = SQ3F*nz*nx;     d2[2][1] = SQ3F*nx*ny;     d2[2][2] = 1.5f*ny*ny - 0.5f;
            d2[2][3] = SQ3F*ny*nz;     d2[2][4] = 0.5f*SQ3F*(nz*nz - nx*nx);
            d2[3][0] = nz*wx + wz*nx;  d2[3][1] = nx*wy + wx*ny;  d2[3][2] = SQ3F*ny*wy;
            d2[3][3] = ny*wz + wy*nz;  d2[3][4] = nz*wz - nx*wx;
            d2[4][0] = wz*wx - uz*ux;  d2[4][1] = wx*wy - ux*uy;  d2[4][2] = 0.5f*SQ3F*(wy*wy - uy*uy);
            d2[4][3] = wy*wz - uy*uz;  d2[4][4] = 0.5f*(wz*wz - uz*uz - wx*wx + ux*ux);
#pragma unroll
            for (int n = 0; n < 5; ++n)
#pragma unroll
                for (int m = 0; m < 5; ++m) sD2[e][5*n + m] = d2[n][m];
        }
    }
    __syncthreads();

    // ---------------- prep part 2: uniform rotate, thread = (edge, channel) ----------------
    {
        const int re = tid >> 5;        // edge 0..15
        const int rc = tid & 31;        // channel within group
        float D1r[9], d2l[25];
#pragma unroll
        for (int i = 0; i < 9; ++i) D1r[i] = sD1[re][i];
#pragma unroll
        for (int i = 0; i < 25; ++i) d2l[i] = sD2[re][i];
        ushort* row = sA + re * AST;
        const ushort* sEb = sY + re * YSTH;
        const float* bc = nrm + (size_t)sCtr[re] * 288;
        const float* bn = nrm + (size_t)sNbr[re] * 288;
#pragma unroll
        for (int p = 0; p < 3; ++p) {
            const int cc = rc + 32 * p;
            float x1v[3], x2v[5];
            if (p == 0) {
#pragma unroll
                for (int m = 0; m < 3; ++m) x1v[m] = bc[32 + 32*m + rc];
#pragma unroll
                for (int m = 0; m < 5; ++m) x2v[m] = bc[128 + 32*m + rc];
            } else if (p == 1) {
#pragma unroll
                for (int m = 0; m < 3; ++m) x1v[m] = bf2f(sEb[32 + 32*m + rc]);
#pragma unroll
                for (int m = 0; m < 5; ++m) x2v[m] = bf2f(sEb[128 + 32*m + rc]);
            } else {
#pragma unroll
                for (int m = 0; m < 3; ++m) x1v[m] = bn[32 + 32*m + rc];
#pragma unroll
                for (int m = 0; m < 5; ++m) x2v[m] = bn[128 + 32*m + rc];
            }
            float r0 = D1r[0]*x1v[0] + D1r[1]*x1v[1] + D1r[2]*x1v[2];
            float r1 = D1r[3]*x1v[0] + D1r[4]*x1v[1] + D1r[5]*x1v[2];
            float r2 = D1r[6]*x1v[0] + D1r[7]*x1v[1] + D1r[8]*x1v[2];
            float t[5];
#pragma unroll
            for (int m = 0; m < 5; ++m)
                t[m] = d2l[5*m+0]*x2v[0] + d2l[5*m+1]*x2v[1] + d2l[5*m+2]*x2v[2]
                     + d2l[5*m+3]*x2v[3] + d2l[5*m+4]*x2v[4];
            row[SEG0 + 96  + cc] = f2bf(r1);
            row[SEG0 + 192 + cc] = f2bf(t[2]);
            row[SEGP1 + cc]      = f2bf(r2);
            row[SEGP1 + 96 + cc] = f2bf(t[3]);
            row[SEGM1 + cc]      = f2bf(r0);
            row[SEGM1 + 96 + cc] = f2bf(t[1]);
            row[SEGP2 + cc]      = f2bf(t[4]);
            row[SEGM2 + cc]      = f2bf(t[0]);
        }
    }
    __syncthreads();

    // ---------------- MFMA GEMM phase: 28 tiles across 8 waves ----------------
    for (int t = wv; t < 28; t += 8) {
        int kbase, nch, yoff, pbase; float scale;
        if (t < 10)      { kbase = SEG0;  nch = 9;  yoff = t*16;          scale = S0F; pbase = PK1 + t*9*512; }
        else if (t < 18) { kbase = SEGP1; nch = 12; yoff = 160+(t-10)*16; scale = S1F; pbase = PK2 + (t-10)*12*512; }
        else if (t < 22) { kbase = SEGP2; nch = 6;  yoff = 288+(t-18)*16; scale = S2F; pbase = PK3 + (t-18)*6*512; }
        else             { kbase = SEGL;  nch = 4;  yoff = 352+(t-22)*16; scale = SEF; pbase = PK4 + (t-22)*4*512; }
        f32x4 acc = {0.f, 0.f, 0.f, 0.f};
        const ushort* pa = sA + (lane & 15) * AST + kbase + (lane >> 4) * 8;
        const ushort* pb = pk + pbase + lane * 8;
        for (int ch = 0; ch < nch; ++ch) {
            bf16x8 a = *reinterpret_cast<const bf16x8*>(pa + ch * 32);
            bf16x8 b = *reinterpret_cast<const bf16x8*>(pb + ch * 512);
            acc = __builtin_amdgcn_mfma_f32_16x16x32_bf16(a, b, acc, 0, 0, 0);
        }
        const int col = yoff + (lane & 15);
        const int r0 = (lane >> 4) * 4;
        float bv = (t >= 22) ? benv[col - 352] : 0.f;
#pragma unroll
        for (int j = 0; j < 4; ++j)
            sY[(r0 + j) * YSTH + col] = f2bf(acc[j] * scale + bv);
    }
    __syncthreads();

    // ---------------- stage 2a: gates, gated n-frame A-matrix (144 x 32, stride PST) ----------------
    const int e2 = tid & 15, c = tid >> 4;   // c in 0..31
    const ushort* yrow = sY + e2 * YSTH;
    {
        float y0v = bf2f(yrow[Y0o + c]);
        float scv = y0v / (1.f + expf(-y0v));
        float gg1 = 1.f / (1.f + expf(-bf2f(yrow[Y0o + 32 + c])));
        float gg2 = 1.f / (1.f + expf(-bf2f(yrow[Y0o + 64 + c])));
        sA[(0   + e2)*PST + c] = f2bf(scv);
        sA[(16  + e2)*PST + c] = f2bf(bf2f(yrow[Y1Mo  + c]) * gg1);
        sA[(32  + e2)*PST + c] = f2bf(bf2f(yrow[Y10o  + c]) * gg1);
        sA[(48  + e2)*PST + c] = f2bf(bf2f(yrow[Y1Po  + c]) * gg1);
        sA[(64  + e2)*PST + c] = f2bf(bf2f(yrow[Y2M2o + c]) * gg2);
        sA[(80  + e2)*PST + c] = f2bf(bf2f(yrow[Y2M1o + c]) * gg2);
        sA[(96  + e2)*PST + c] = f2bf(bf2f(yrow[Y20o  + c]) * gg2);
        sA[(112 + e2)*PST + c] = f2bf(bf2f(yrow[Y2P1o + c]) * gg2);
        sA[(128 + e2)*PST + c] = f2bf(bf2f(yrow[Y2P2o + c]) * gg2);
    }
    __syncthreads();

    // ---------------- proj MFMA: 18 tiles (9 row x 2 col) across 8 waves ----------------
    f32x4 pacc[3];
#pragma unroll
    for (int q = 0; q < 3; ++q) {
        const int t = wv + 8*q;
        if (t < 18) {
            const int rt = t >> 1, ct = t & 1;
            const int wpi = (rt == 0) ? 0 : (rt < 4) ? 1 : 2;
            bf16x8 a = *reinterpret_cast<const bf16x8*>(sA + (rt*16 + (lane & 15))*PST + (lane >> 4)*8);
            bf16x8 b = *reinterpret_cast<const bf16x8*>(pk + PKP + wpi*1024 + ct*512 + lane*8);
            f32x4 z = {0.f, 0.f, 0.f, 0.f};
            pacc[q] = __builtin_amdgcn_mfma_f32_16x16x32_bf16(a, b, z, 0, 0, 0);
        }
    }
    __syncthreads();   // A reads done -> overwrite sA with sP (f32)

    float* sPf = reinterpret_cast<float*>(sA);
#pragma unroll
    for (int q = 0; q < 3; ++q) {
        const int t = wv + 8*q;
        if (t < 18) {
            const int rt = t >> 1, ct = t & 1;
            const int col = ct*16 + (lane & 15);
#pragma unroll
            for (int j = 0; j < 4; ++j) {
                const int rw = rt*16 + (lane >> 4)*4 + j;
                sPf[rw*PST + col] = pacc[q][j];
            }
        }
    }
    __syncthreads();

    // ---------------- stage 2b: rotate-back + env gate -> msg write (or atomic fallback) ----------------
    const int d = c;
    {
        float wv0g = bf2f(yrow[WENVo + d]);
        float m0v = (sPf[e2*PST + d] * SCF + bp0[d]) * wv0g;

        float p1v[3], p2v[5];
#pragma unroll
        for (int m = 0; m < 3; ++m) p1v[m] = sPf[(16 + 16*m + e2)*PST + d];
#pragma unroll
        for (int m = 0; m < 5; ++m) p2v[m] = sPf[(64 + 16*m + e2)*PST + d];

        float wv1g = bf2f(yrow[WENVo + 32 + d]) * SCF;
        float wv2g = bf2f(yrow[WENVo + 64 + d]) * SCF;

        float o1[3], o2[5];
#pragma unroll
        for (int mm = 0; mm < 3; ++mm)
            o1[mm] = (sD1[e2][mm]*p1v[0] + sD1[e2][3+mm]*p1v[1] + sD1[e2][6+mm]*p1v[2]) * wv1g;
#pragma unroll
        for (int mm = 0; mm < 5; ++mm)
            o2[mm] = (sD2[e2][mm]*p2v[0] + sD2[e2][5+mm]*p2v[1] + sD2[e2][10+mm]*p2v[2]
                    + sD2[e2][15+mm]*p2v[3] + sD2[e2][20+mm]*p2v[4]) * wv2g;

        if (msg) {
            ushort* mr = msg + (size_t)(blockIdx.x * EPB + e2) * 288;
            mr[d] = f2bf(m0v);
#pragma unroll
            for (int mm = 0; mm < 3; ++mm) mr[32 + 3*d + mm] = f2bf(o1[mm]);
#pragma unroll
            for (int mm = 0; mm < 5; ++mm) mr[128 + 5*d + mm] = f2bf(o2[mm]);
        } else {
            float* ob = out + (size_t)sCtr[e2] * 288;
            atomicAdd(ob + d, COEFF * m0v);
#pragma unroll
            for (int mm = 0; mm < 3; ++mm) atomicAdd(ob + 32 + 3*d + mm, COEFF * o1[mm]);
#pragma unroll
            for (int mm = 0; mm < 5; ++mm) atomicAdd(ob + 128 + 5*d + mm, COEFF * o2[mm]);
        }
    }
}

extern "C" void kernel_launch(void* const* d_in, const int* in_sizes, int n_in,
                              void* d_out, int out_size, void* d_ws, size_t ws_size,
                              hipStream_t stream)
{
    const float* latents = (const float*)d_in[0];
    const float* nf      = (const float*)d_in[1];
    const float* efe     = (const float*)d_in[2];
    const float* evec    = (const float*)d_in[3];
    const int*   eidx    = (const int*)d_in[5];
    const int*   act     = (const int*)d_in[6];
    const float* g0n = (const float*)d_in[7];
    const float* b0n = (const float*)d_in[8];
    const float* g1n = (const float*)d_in[9];
    const float* g2n = (const float*)d_in[10];
    const float* g0e = (const float*)d_in[11];
    const float* b0e = (const float*)d_in[12];
    const float* g1e = (const float*)d_in[13];
    const float* g2e = (const float*)d_in[14];
    const float* w0s = (const float*)d_in[15];
    const float* w01 = (const float*)d_in[16];
    const float* w02 = (const float*)d_in[17];
    const float* wr11 = (const float*)d_in[18];
    const float* wi11 = (const float*)d_in[19];
    const float* wr12 = (const float*)d_in[20];
    const float* wi12 = (const float*)d_in[21];
    const float* wr22 = (const float*)d_in[22];
    const float* wi22 = (const float*)d_in[23];
    const float* wp0 = (const float*)d_in[24];
    const float* bp0 = (const float*)d_in[25];
    const float* wp1 = (const float*)d_in[26];
    const float* wp2 = (const float*)d_in[27];
    const float* wenv = (const float*)d_in[28];
    const float* benv = (const float*)d_in[29];
    float* out = (float*)d_out;

    char* ws = (char*)d_ws;
    float* nrm  = (float*)(ws + WS_NRM);
    ushort* pkw = (ushort*)(ws + WS_PK);
    const bool use_msg = (ws_size >= WS_REQ);
    int* counts = (int*)(ws + WS_CNT);
    int* offs   = (int*)(ws + WS_OFF);
    int* curs   = (int*)(ws + WS_CUR);
    int* elist  = (int*)(ws + WS_EL);
    ushort* msg = (ushort*)(ws + WS_MSG);

    pack_k<<<(PKTOT + 255) / 256, 256, 0, stream>>>(w0s, w01, w02, wr11, wi11, wr12, wi12,
                                                    wr22, wi22, wenv, wp0, wp1, wp2, pkw);
    node_norm_k<<<(NN + 3) / 4, 256, 0, stream>>>(nf, g0n, b0n, g1n, g2n, nrm,
                                                  use_msg ? nullptr : out);
    if (use_msg) {
        zero_k<<<(NN + 255) / 256, 256, 0, stream>>>(counts);
        hist_k<<<(EE + 255) / 256, 256, 0, stream>>>(eidx, act, counts);
        scan_k<<<1, 256, 0, stream>>>(counts, offs, curs);
        scatter_k<<<(EE + 255) / 256, 256, 0, stream>>>(eidx, act, curs, elist);
    }
    edge_k<<<EE / EPB, 512, 0, stream>>>(latents, efe, evec, eidx, act,
        g0e, b0e, g1e, g2e, pkw, bp0, benv, nrm, use_msg ? msg : nullptr, out);
    if (use_msg) {
        gather_k<<<(NN + 3) / 4, 256, 0, stream>>>(msg, offs, counts, elist, nf, out);
    }
}

// Round 8
// 305.764 us; speedup vs baseline: 1.9295x; 1.0246x over previous
//
#include <hip/hip_runtime.h>
#include <hip/hip_bf16.h>
#include <math.h>

#define NN 10000
#define EE 100000
#define EPB 16          // edges per block
#define AST 1000        // sA row stride (ushorts)
#define YSTH 456        // sY row stride (ushorts, bf16)
#define PST 40          // proj area row stride (ushorts / floats)

// staged-input segment offsets within an sA row (ushort index)
#define SEG0 0
#define SEGP1 288
#define SEGM1 480
#define SEGP2 672
#define SEGM2 768
#define SEGL 864

// sY per-edge layout (bf16)
#define Y0o   0
#define Y10o  96
#define Y20o  128
#define Y1Po  160
#define Y1Mo  192
#define Y2P1o 224
#define Y2M1o 256
#define Y2P2o 288
#define Y2M2o 320
#define WENVo 352

// packed-weight region offsets (ushort index)
#define PK1 0
#define PK2 46080
#define PK3 95232
#define PK4 107520
#define PKP 119808
#define PKTOT 122880

// workspace layout (bytes)
#define WS_NRM 0
#define WS_PK  11520000
#define WS_CNT 11765760
#define WS_OFF 11831296
#define WS_CUR 11896832
#define WS_EL  11962368
#define WS_MSG 12486656
#define WS_REQ (WS_MSG + (size_t)EE*288*2)

#define SQ3F  1.7320508075688772f
#define S0F   0.05892556509887896f
#define S1F   0.07216878364870323f
#define S2F   0.10206207261596575f
#define SEF   0.08838834764831845f
#define SCF   0.17677669529663687f
#define COLDF 0.8944271909999159f
#define COEFF 0.1414213562373095f

typedef __attribute__((ext_vector_type(8))) short bf16x8;
typedef __attribute__((ext_vector_type(4))) float f32x4;

__device__ __forceinline__ ushort f2bf(float f) {
    __hip_bfloat16 h = __float2bfloat16(f);
    return __builtin_bit_cast(unsigned short, h);
}
__device__ __forceinline__ float bf2f(ushort u) {
    union { unsigned u; float f; } v; v.u = (unsigned)u << 16; return v.f;
}
__device__ __forceinline__ float fsig(float x) {
    return __builtin_amdgcn_rcpf(1.f + __expf(-x));
}

__device__ __forceinline__ int planar(int k) {
    if (k < 32) return k;
    if (k < 128) { int c = (k - 32) / 3, m = (k - 32) % 3; return 32 + 32*m + c; }
    int c = (k - 128) / 5, m = (k - 128) % 5; return 128 + 32*m + c;
}

// ---------------- weight pre-pack ----------------
__global__ __launch_bounds__(256) void pack_k(
    const float* __restrict__ w0s, const float* __restrict__ w01, const float* __restrict__ w02,
    const float* __restrict__ wr11, const float* __restrict__ wi11,
    const float* __restrict__ wr12, const float* __restrict__ wi12,
    const float* __restrict__ wr22, const float* __restrict__ wi22,
    const float* __restrict__ wenv,
    const float* __restrict__ wp0, const float* __restrict__ wp1, const float* __restrict__ wp2,
    ushort* __restrict__ pk)
{
    int i = blockIdx.x * 256 + threadIdx.x;
    if (i >= PKTOT) return;
    float val;
    if (i < PK2) {
        int idx = i - PK1;
        int tile = idx / 4608, rem = idx % 4608;
        int chunk = rem / 512, rem2 = rem % 512;
        int lane = rem2 / 8, j = rem2 % 8;
        int col = tile * 16 + (lane & 15);
        int k = chunk * 32 + (lane >> 4) * 8 + j;
        if (col < 96)       val = w0s[col * 288 + k];
        else if (col < 128) val = w01[(col - 96) * 288 + k];
        else                val = w02[(col - 128) * 288 + k];
    } else if (i < PK3) {
        int idx = i - PK2;
        int tile = idx / 6144, rem = idx % 6144;
        int chunk = rem / 512, rem2 = rem % 512;
        int lane = rem2 / 8, j = rem2 % 8;
        int col = tile * 16 + (lane & 15);
        int k = chunk * 32 + (lane >> 4) * 8 + j;
        int grp = col >> 5, c = col & 31;
        if (k < 192) {
            val = (grp == 0) ? wr11[c*192 + k] : (grp == 1) ? wi11[c*192 + k]
                : (grp == 2) ? wr12[c*192 + k] : wi12[c*192 + k];
        } else {
            int kk = k - 192;
            val = (grp == 0) ? -wi11[c*192 + kk] : (grp == 1) ? wr11[c*192 + kk]
                : (grp == 2) ? -wi12[c*192 + kk] : wr12[c*192 + kk];
        }
    } else if (i < PK4) {
        int idx = i - PK3;
        int tile = idx / 3072, rem = idx % 3072;
        int chunk = rem / 512, rem2 = rem % 512;
        int lane = rem2 / 8, j = rem2 % 8;
        int col = tile * 16 + (lane & 15);
        int k = chunk * 32 + (lane >> 4) * 8 + j;
        int grp = col >> 5, c = col & 31;
        if (k < 96) val = grp ? wi22[c*96 + k] : wr22[c*96 + k];
        else        val = grp ? wr22[c*96 + k - 96] : -wi22[c*96 + k - 96];
    } else if (i < PKP) {
        int idx = i - PK4;
        int tile = idx / 2048, rem = idx % 2048;
        int chunk = rem / 512, rem2 = rem % 512;
        int lane = rem2 / 8, j = rem2 % 8;
        int col = tile * 16 + (lane & 15);
        int k = chunk * 32 + (lane >> 4) * 8 + j;
        val = wenv[col * 128 + k];
    } else {
        int idx = i - PKP;
        int wpi = idx / 1024, rem = idx % 1024;
        int ct = rem / 512, rem2 = rem % 512;
        int lane = rem2 / 8, j = rem2 % 8;
        int col = ct * 16 + (lane & 15);
        int k = (lane >> 4) * 8 + j;
        const float* w = (wpi == 0) ? wp0 : (wpi == 1) ? wp1 : wp2;
        val = w[col * 32 + k];
    }
    pk[i] = f2bf(val);
}

// ---------------- node SLN -> planar nrm ----------------
__global__ __launch_bounds__(256) void node_norm_k(
    const float* __restrict__ nf,
    const float* __restrict__ g0, const float* __restrict__ b0,
    const float* __restrict__ g1, const float* __restrict__ g2,
    float* __restrict__ nrm, float* __restrict__ out)
{
    int row = blockIdx.x * 4 + (threadIdx.x >> 6);
    if (row >= NN) return;
    int lane = threadIdx.x & 63;
    const float* r = nf + (size_t)row * 288;
    float v0 = r[lane];
    float v1 = r[lane + 64];
    float v2 = r[lane + 128];
    float v3 = r[lane + 192];
    float v4 = (lane < 32) ? r[lane + 256] : 0.f;
    float s0 = 0.f, s0q = 0.f, q1 = 0.f, q2 = 0.f;
    if (lane < 32) { s0 = v0; s0q = v0*v0; } else { q1 = v0*v0; }
    q1 += v1*v1;
    q2 += v2*v2 + v3*v3 + v4*v4;
#pragma unroll
    for (int m = 1; m < 64; m <<= 1) {
        s0  += __shfl_xor(s0, m);
        s0q += __shfl_xor(s0q, m);
        q1  += __shfl_xor(q1, m);
        q2  += __shfl_xor(q2, m);
    }
    float mu  = s0 * (1.f/32.f);
    float var = s0q * (1.f/32.f) - mu*mu;
    float rs0 = rsqrtf(var + 1e-8f);
    float rv  = 0.5f * (q1 * (1.f/96.f) + q2 * (1.f/160.f));
    float rs  = rsqrtf(rv + 1e-8f);
    float* nr = nrm + (size_t)row * 288;
    {
        float res;
        if (lane < 32) res = (v0 - mu) * rs0 * g0[lane] + b0[lane];
        else { int c = (lane - 32) / 3; res = v0 * rs * g1[c]; }
        nr[planar(lane)] = res;
    }
    { int k = lane + 64;  int c = (k - 32) / 3;  nr[planar(k)] = v1 * rs * g1[c]; }
    { int k = lane + 128; int c = (k - 128) / 5; nr[planar(k)] = v2 * rs * g2[c]; }
    { int k = lane + 192; int c = (k - 128) / 5; nr[planar(k)] = v3 * rs * g2[c]; }
    if (lane < 32) { int k = lane + 256; int c = (k - 128) / 5; nr[planar(k)] = v4 * rs * g2[c]; }
    if (out) {
        float* orow = out + (size_t)row * 288;
        orow[lane]       = COLDF * v0;
        orow[lane + 64]  = COLDF * v1;
        orow[lane + 128] = COLDF * v2;
        orow[lane + 192] = COLDF * v3;
        if (lane < 32) orow[lane + 256] = COLDF * v4;
    }
}

// ---------------- CSR build ----------------
__global__ __launch_bounds__(256) void zero_k(int* __restrict__ counts) {
    int i = blockIdx.x * 256 + threadIdx.x;
    if (i < NN) counts[i] = 0;
}
__global__ __launch_bounds__(256) void hist_k(
    const int* __restrict__ eidx, const int* __restrict__ act, int* __restrict__ counts) {
    int e = blockIdx.x * 256 + threadIdx.x;
    if (e >= EE) return;
    atomicAdd(&counts[eidx[act[e]]], 1);
}
__global__ __launch_bounds__(256) void scan_k(
    const int* __restrict__ counts, int* __restrict__ offs, int* __restrict__ curs) {
    __shared__ int sbuf[256];
    __shared__ int scarry;
    if (threadIdx.x == 0) scarry = 0;
    __syncthreads();
    for (int base = 0; base < NN; base += 256) {
        int i = base + threadIdx.x;
        int v = (i < NN) ? counts[i] : 0;
        sbuf[threadIdx.x] = v;
        __syncthreads();
        for (int off = 1; off < 256; off <<= 1) {
            int t = (threadIdx.x >= off) ? sbuf[threadIdx.x - off] : 0;
            __syncthreads();
            sbuf[threadIdx.x] += t;
            __syncthreads();
        }
        int excl = sbuf[threadIdx.x] - v;
        if (i < NN) { int o = scarry + excl; offs[i] = o; curs[i] = o; }
        __syncthreads();
        if (threadIdx.x == 255) scarry += sbuf[255];
        __syncthreads();
    }
}
// eslot[e] = destination slot (node-sorted) for edge e's message
__global__ __launch_bounds__(256) void scatter_k(
    const int* __restrict__ eidx, const int* __restrict__ act,
    int* __restrict__ curs, int* __restrict__ eslot) {
    int e = blockIdx.x * 256 + threadIdx.x;
    if (e >= EE) return;
    int pos = atomicAdd(&curs[eidx[act[e]]], 1);
    eslot[e] = pos;
}

// ---------------- gather: out = c_old*nf + c_new * sum(msg[start..start+cnt)) ----------------
__global__ __launch_bounds__(256) void gather_k(
    const ushort* __restrict__ msg, const int* __restrict__ offs,
    const int* __restrict__ counts,
    const float* __restrict__ nf, float* __restrict__ out)
{
    int node = blockIdx.x * 4 + (threadIdx.x >> 6);
    if (node >= NN) return;
    int lane = threadIdx.x & 63;
    int start = offs[node], cnt = counts[node];
    float a0 = 0.f, a1 = 0.f, a2 = 0.f, a3 = 0.f, a4 = 0.f;
    const ushort* mr = msg + (size_t)start * 288;
    for (int i = 0; i < cnt; ++i, mr += 288) {
        a0 += bf2f(mr[lane]);
        a1 += bf2f(mr[lane + 64]);
        a2 += bf2f(mr[lane + 128]);
        a3 += bf2f(mr[lane + 192]);
        if (lane < 32) a4 += bf2f(mr[lane + 256]);
    }
    const float* r = nf + (size_t)node * 288;
    float* o = out + (size_t)node * 288;
    o[lane]       = COLDF * r[lane]       + COEFF * a0;
    o[lane + 64]  = COLDF * r[lane + 64]  + COEFF * a1;
    o[lane + 128] = COLDF * r[lane + 128] + COEFF * a2;
    o[lane + 192] = COLDF * r[lane + 192] + COEFF * a3;
    if (lane < 32) o[lane + 256] = COLDF * r[lane + 256] + COEFF * a4;
}

// ---------------- fused edge kernel: 512 threads / 16 edges ----------------
__global__ __launch_bounds__(512, 6) void edge_k(
    const float* __restrict__ lat, const float* __restrict__ ef,
    const float* __restrict__ evec,
    const int* __restrict__ eidx, const int* __restrict__ act,
    const int* __restrict__ eslot,
    const float* __restrict__ g0e, const float* __restrict__ b0e,
    const float* __restrict__ g1e, const float* __restrict__ g2e,
    const ushort* __restrict__ pk,
    const float* __restrict__ bp0, const float* __restrict__ benv,
    const float* __restrict__ nrm, ushort* __restrict__ msg, float* __restrict__ out)
{
    __shared__ __align__(16) ushort sA[EPB * AST];   // 32000B; reused proj-A then sP (f32)
    __shared__ __align__(16) ushort sY[EPB * YSTH];  // 14592B
    __shared__ float sD1[EPB][12];
    __shared__ float sD2[EPB][28];
    __shared__ int sAe[EPB], sCtr[EPB], sNbr[EPB], sSlot[EPB];

    const int tid = threadIdx.x;
    const int wv = tid >> 6, lane = tid & 63;

    if (tid < EPB) {
        int ae = act[blockIdx.x * EPB + tid];
        sAe[tid] = ae;
        sCtr[tid] = eidx[ae];
        sNbr[tid] = eidx[EE + ae];
        sSlot[tid] = eslot ? eslot[blockIdx.x * EPB + tid] : 0;
    }
    __syncthreads();

    // ---------------- prep part 1: wave per edge, 2 iterations ----------------
    for (int it = 0; it < 2; ++it) {
        const int e = it * 8 + wv;
        const int ae = sAe[e];
        const int ctr = sCtr[e], nbr = sNbr[e];
        ushort* row = sA + e * AST;
        ushort* sEb = sY + e * YSTH;
        const float* efr = ef + (size_t)ae * 288;

        float ev0 = efr[lane];
        float ev1 = efr[lane + 64];
        float ev2 = efr[lane + 128];
        float ev3 = efr[lane + 192];
        float ev4 = (lane < 32) ? efr[lane + 256] : 0.f;
        float s0 = 0.f, s0q = 0.f, q1 = 0.f, q2 = 0.f;
        if (lane < 32) { s0 = ev0; s0q = ev0*ev0; } else { q1 = ev0*ev0; }
        q1 += ev1*ev1;
        q2 += ev2*ev2 + ev3*ev3 + ev4*ev4;
#pragma unroll
        for (int m = 1; m < 64; m <<= 1) {
            s0  += __shfl_xor(s0, m);
            s0q += __shfl_xor(s0q, m);
            q1  += __shfl_xor(q1, m);
            q2  += __shfl_xor(q2, m);
        }
        float mu  = s0 * (1.f/32.f);
        float rs0 = rsqrtf(s0q*(1.f/32.f) - mu*mu + 1e-8f);
        float rs  = rsqrtf(0.5f*(q1*(1.f/96.f) + q2*(1.f/160.f)) + 1e-8f);

        if (lane >= 32) { int c = (lane-32)/3, m = (lane-32)%3; sEb[32 + 32*m + c] = f2bf(ev0 * rs * g1e[c]); }
        { int k = lane+64;  int c = (k-32)/3,  m = (k-32)%3;  sEb[32 + 32*m + c]  = f2bf(ev1 * rs * g1e[c]); }
        { int k = lane+128; int c = (k-128)/5, m = (k-128)%5; sEb[128 + 32*m + c] = f2bf(ev2 * rs * g2e[c]); }
        { int k = lane+192; int c = (k-128)/5, m = (k-128)%5; sEb[128 + 32*m + c] = f2bf(ev3 * rs * g2e[c]); }
        if (lane < 32) { int k = lane+256; int c = (k-128)/5, m = (k-128)%5; sEb[128 + 32*m + c] = f2bf(ev4 * rs * g2e[c]); }

        if (lane < 32) {
            row[SEG0 + 32 + lane] = f2bf((ev0 - mu) * rs0 * g0e[lane] + b0e[lane]);
            row[SEG0 + lane]      = f2bf(nrm[(size_t)ctr*288 + lane]);
            row[SEG0 + 64 + lane] = f2bf(nrm[(size_t)nbr*288 + lane]);
        }
        {
            const float* lr = lat + (size_t)ae * 128;
            row[SEGL + lane]      = f2bf(lr[lane]);
            row[SEGL + 64 + lane] = f2bf(lr[lane + 64]);
        }

        // local frame + analytic l=2 Wigner (redundant across lanes; lane 0 stores)
        float vx = evec[3*ae], vy = evec[3*ae+1], vz = evec[3*ae+2];
        float nnv = fmaxf(sqrtf(vx*vx + vy*vy + vz*vz), 1e-9f);
        float nx = vx/nnv, ny = vy/nnv, nz = vz/nnv;
        float ax, az;
        if (fabsf(nx) < 0.9f) { ax = 1.f; az = 0.f; } else { ax = 0.f; az = 1.f; }
        float adn = ax*nx + az*nz;
        float ux = ax - adn*nx, uy = -adn*ny, uz = az - adn*nz;
        float un = fmaxf(sqrtf(ux*ux + uy*uy + uz*uz), 1e-9f);
        ux /= un; uy /= un; uz /= un;
        float wx = uy*nz - uz*ny, wy = uz*nx - ux*nz, wz = ux*ny - uy*nx;

        if (lane == 0) {
            sD1[e][0] = ux; sD1[e][1] = uy; sD1[e][2] = uz;
            sD1[e][3] = nx; sD1[e][4] = ny; sD1[e][5] = nz;
            sD1[e][6] = wx; sD1[e][7] = wy; sD1[e][8] = wz;
            float d2[5][5];
            d2[0][0] = wz*ux + uz*wx;  d2[0][1] = wx*uy + ux*wy;  d2[0][2] = SQ3F*wy*uy;
            d2[0][3] = wy*uz + uy*wz;  d2[0][4] = wz*uz - wx*ux;
            d2[1][0] = uz*nx + nz*ux;  d2[1][1] = ux*ny + nx*uy;  d2[1][2] = SQ3F*uy*ny;
            d2[1][3] = uy*nz + ny*uz;  d2[1][4] = uz*nz - ux*nx;
            d2[2][0] = SQ3F*nz*nx;     d2[2][1] = SQ3F*nx*ny;     d2[2][2] = 1.5f*ny*ny - 0.5f;
            d2[2][3] = SQ3F*ny*nz;     d2[2][4] = 0.5f*SQ3F*(nz*nz - nx*nx);
            d2[3][0] = nz*wx + wz*nx;  d2[3][1] = nx*wy + wx*ny;  d2[3][2] = SQ3F*ny*wy;
            d2[3][3] = ny*wz + wy*nz;  d2[3][4] = nz*wz - nx*wx;
            d2[4][0] = wz*wx - uz*ux;  d2[4][1] = wx*wy - ux*uy;  d2[4][2] = 0.5f*SQ3F*(wy*wy - uy*uy);
            d2[4][3] = wy*wz - uy*uz;  d2[4][4] = 0.5f*(wz*wz - uz*uz - wx*wx + ux*ux);
#pragma unroll
            for (int n = 0; n < 5; ++n)
#pragma unroll
                for (int m = 0; m < 5; ++m) sD2[e][5*n + m] = d2[n][m];
        }
    }
    __syncthreads();

    // ---------------- prep part 2: uniform rotate, thread = (edge, channel) ----------------
    {
        const int re = tid >> 5;        // edge 0..15
        const int rc = tid & 31;        // channel within group
        const float* bc = nrm + (size_t)sCtr[re] * 288;
        const float* bn = nrm + (size_t)sNbr[re] * 288;
        // hoist ALL global loads first (ILP)
        float c1v[3], c2v[5], n1v[3], n2v[5];
#pragma unroll
        for (int m = 0; m < 3; ++m) { c1v[m] = bc[32 + 32*m + rc]; n1v[m] = bn[32 + 32*m + rc]; }
#pragma unroll
        for (int m = 0; m < 5; ++m) { c2v[m] = bc[128 + 32*m + rc]; n2v[m] = bn[128 + 32*m + rc]; }
        float D1r[9], d2l[25];
#pragma unroll
        for (int i = 0; i < 9; ++i) D1r[i] = sD1[re][i];
#pragma unroll
        for (int i = 0; i < 25; ++i) d2l[i] = sD2[re][i];
        ushort* row = sA + re * AST;
        const ushort* sEb = sY + re * YSTH;
        float e1v[3], e2v[5];
#pragma unroll
        for (int m = 0; m < 3; ++m) e1v[m] = bf2f(sEb[32 + 32*m + rc]);
#pragma unroll
        for (int m = 0; m < 5; ++m) e2v[m] = bf2f(sEb[128 + 32*m + rc]);
#pragma unroll
        for (int p = 0; p < 3; ++p) {
            const int cc = rc + 32 * p;
            float x1v[3], x2v[5];
#pragma unroll
            for (int m = 0; m < 3; ++m) x1v[m] = (p == 0) ? c1v[m] : (p == 1) ? e1v[m] : n1v[m];
#pragma unroll
            for (int m = 0; m < 5; ++m) x2v[m] = (p == 0) ? c2v[m] : (p == 1) ? e2v[m] : n2v[m];
            float r0 = D1r[0]*x1v[0] + D1r[1]*x1v[1] + D1r[2]*x1v[2];
            float r1 = D1r[3]*x1v[0] + D1r[4]*x1v[1] + D1r[5]*x1v[2];
            float r2 = D1r[6]*x1v[0] + D1r[7]*x1v[1] + D1r[8]*x1v[2];
            float t[5];
#pragma unroll
            for (int m = 0; m < 5; ++m)
                t[m] = d2l[5*m+0]*x2v[0] + d2l[5*m+1]*x2v[1] + d2l[5*m+2]*x2v[2]
                     + d2l[5*m+3]*x2v[3] + d2l[5*m+4]*x2v[4];
            row[SEG0 + 96  + cc] = f2bf(r1);
            row[SEG0 + 192 + cc] = f2bf(t[2]);
            row[SEGP1 + cc]      = f2bf(r2);
            row[SEGP1 + 96 + cc] = f2bf(t[3]);
            row[SEGM1 + cc]      = f2bf(r0);
            row[SEGM1 + 96 + cc] = f2bf(t[1]);
            row[SEGP2 + cc]      = f2bf(t[4]);
            row[SEGM2 + cc]      = f2bf(t[0]);
        }
    }
    __syncthreads();

    // ---------------- MFMA GEMM phase: 28 tiles across 8 waves ----------------
    for (int t = wv; t < 28; t += 8) {
        int kbase, nch, yoff, pbase; float scale;
        if (t < 10)      { kbase = SEG0;  nch = 9;  yoff = t*16;          scale = S0F; pbase = PK1 + t*9*512; }
        else if (t < 18) { kbase = SEGP1; nch = 12; yoff = 160+(t-10)*16; scale = S1F; pbase = PK2 + (t-10)*12*512; }
        else if (t < 22) { kbase = SEGP2; nch = 6;  yoff = 288+(t-18)*16; scale = S2F; pbase = PK3 + (t-18)*6*512; }
        else             { kbase = SEGL;  nch = 4;  yoff = 352+(t-22)*16; scale = SEF; pbase = PK4 + (t-22)*4*512; }
        f32x4 acc = {0.f, 0.f, 0.f, 0.f};
        const ushort* pa = sA + (lane & 15) * AST + kbase + (lane >> 4) * 8;
        const ushort* pb = pk + pbase + lane * 8;
        for (int ch = 0; ch < nch; ++ch) {
            bf16x8 a = *reinterpret_cast<const bf16x8*>(pa + ch * 32);
            bf16x8 b = *reinterpret_cast<const bf16x8*>(pb + ch * 512);
            acc = __builtin_amdgcn_mfma_f32_16x16x32_bf16(a, b, acc, 0, 0, 0);
        }
        const int col = yoff + (lane & 15);
        const int r0 = (lane >> 4) * 4;
        float bv = (t >= 22) ? benv[col - 352] : 0.f;
#pragma unroll
        for (int j = 0; j < 4; ++j)
            sY[(r0 + j) * YSTH + col] = f2bf(acc[j] * scale + bv);
    }
    __syncthreads();

    // ---------------- stage 2a: gates, gated n-frame A-matrix (144 x 32, stride PST) ----------------
    const int e2 = tid & 15, c = tid >> 4;   // c in 0..31
    const ushort* yrow = sY + e2 * YSTH;
    {
        float y0v = bf2f(yrow[Y0o + c]);
        float scv = y0v * fsig(y0v);
        float gg1 = fsig(bf2f(yrow[Y0o + 32 + c]));
        float gg2 = fsig(bf2f(yrow[Y0o + 64 + c]));
        sA[(0   + e2)*PST + c] = f2bf(scv);
        sA[(16  + e2)*PST + c] = f2bf(bf2f(yrow[Y1Mo  + c]) * gg1);
        sA[(32  + e2)*PST + c] = f2bf(bf2f(yrow[Y10o  + c]) * gg1);
        sA[(48  + e2)*PST + c] = f2bf(bf2f(yrow[Y1Po  + c]) * gg1);
        sA[(64  + e2)*PST + c] = f2bf(bf2f(yrow[Y2M2o + c]) * gg2);
        sA[(80  + e2)*PST + c] = f2bf(bf2f(yrow[Y2M1o + c]) * gg2);
        sA[(96  + e2)*PST + c] = f2bf(bf2f(yrow[Y20o  + c]) * gg2);
        sA[(112 + e2)*PST + c] = f2bf(bf2f(yrow[Y2P1o + c]) * gg2);
        sA[(128 + e2)*PST + c] = f2bf(bf2f(yrow[Y2P2o + c]) * gg2);
    }
    __syncthreads();

    // ---------------- proj MFMA: 18 tiles (9 row x 2 col) across 8 waves ----------------
    f32x4 pacc[3];
#pragma unroll
    for (int q = 0; q < 3; ++q) {
        const int t = wv + 8*q;
        if (t < 18) {
            const int rt = t >> 1, ct = t & 1;
            const int wpi = (rt == 0) ? 0 : (rt < 4) ? 1 : 2;
            bf16x8 a = *reinterpret_cast<const bf16x8*>(sA + (rt*16 + (lane & 15))*PST + (lane >> 4)*8);
            bf16x8 b = *reinterpret_cast<const bf16x8*>(pk + PKP + wpi*1024 + ct*512 + lane*8);
            f32x4 z = {0.f, 0.f, 0.f, 0.f};
            pacc[q] = __builtin_amdgcn_mfma_f32_16x16x32_bf16(a, b, z, 0, 0, 0);
        }
    }
    __syncthreads();   // A reads done -> overwrite sA with sP (f32)

    float* sPf = reinterpret_cast<float*>(sA);
#pragma unroll
    for (int q = 0; q < 3; ++q) {
        const int t = wv + 8*q;
        if (t < 18) {
            const int rt = t >> 1, ct = t & 1;
            const int col = ct*16 + (lane & 15);
#pragma unroll
            for (int j = 0; j < 4; ++j) {
                const int rw = rt*16 + (lane >> 4)*4 + j;
                sPf[rw*PST + col] = pacc[q][j];
            }
        }
    }
    __syncthreads();

    // ---------------- stage 2b: rotate-back + env gate -> msg write (or atomic fallback) ----------------
    const int d = c;
    {
        float wv0g = bf2f(yrow[WENVo + d]);
        float m0v = (sPf[e2*PST + d] * SCF + bp0[d]) * wv0g;

        float p1v[3], p2v[5];
#pragma unroll
        for (int m = 0; m < 3; ++m) p1v[m] = sPf[(16 + 16*m + e2)*PST + d];
#pragma unroll
        for (int m = 0; m < 5; ++m) p2v[m] = sPf[(64 + 16*m + e2)*PST + d];

        float wv1g = bf2f(yrow[WENVo + 32 + d]) * SCF;
        float wv2g = bf2f(yrow[WENVo + 64 + d]) * SCF;

        float o1[3], o2[5];
#pragma unroll
        for (int mm = 0; mm < 3; ++mm)
            o1[mm] = (sD1[e2][mm]*p1v[0] + sD1[e2][3+mm]*p1v[1] + sD1[e2][6+mm]*p1v[2]) * wv1g;
#pragma unroll
        for (int mm = 0; mm < 5; ++mm)
            o2[mm] = (sD2[e2][mm]*p2v[0] + sD2[e2][5+mm]*p2v[1] + sD2[e2][10+mm]*p2v[2]
                    + sD2[e2][15+mm]*p2v[3] + sD2[e2][20+mm]*p2v[4]) * wv2g;

        if (msg) {
            ushort* mr = msg + (size_t)sSlot[e2] * 288;
            mr[d] = f2bf(m0v);
#pragma unroll
            for (int mm = 0; mm < 3; ++mm) mr[32 + 3*d + mm] = f2bf(o1[mm]);
#pragma unroll
            for (int mm = 0; mm < 5; ++mm) mr[128 + 5*d + mm] = f2bf(o2[mm]);
        } else {
            float* ob = out + (size_t)sCtr[e2] * 288;
            atomicAdd(ob + d, COEFF * m0v);
#pragma unroll
            for (int mm = 0; mm < 3; ++mm) atomicAdd(ob + 32 + 3*d + mm, COEFF * o1[mm]);
#pragma unroll
            for (int mm = 0; mm < 5; ++mm) atomicAdd(ob + 128 + 5*d + mm, COEFF * o2[mm]);
        }
    }
}

extern "C" void kernel_launch(void* const* d_in, const int* in_sizes, int n_in,
                              void* d_out, int out_size, void* d_ws, size_t ws_size,
                              hipStream_t stream)
{
    const float* latents = (const float*)d_in[0];
    const float* nf      = (const float*)d_in[1];
    const float* efe     = (const float*)d_in[2];
    const float* evec    = (const float*)d_in[3];
    const int*   eidx    = (const int*)d_in[5];
    const int*   act     = (const int*)d_in[6];
    const float* g0n = (const float*)d_in[7];
    const float* b0n = (const float*)d_in[8];
    const float* g1n = (const float*)d_in[9];
    const float* g2n = (const float*)d_in[10];
    const float* g0e = (const float*)d_in[11];
    const float* b0e = (const float*)d_in[12];
    const float* g1e = (const float*)d_in[13];
    const float* g2e = (const float*)d_in[14];
    const float* w0s = (const float*)d_in[15];
    const float* w01 = (const float*)d_in[16];
    const float* w02 = (const float*)d_in[17];
    const float* wr11 = (const float*)d_in[18];
    const float* wi11 = (const float*)d_in[19];
    const float* wr12 = (const float*)d_in[20];
    const float* wi12 = (const float*)d_in[21];
    const float* wr22 = (const float*)d_in[22];
    const float* wi22 = (const float*)d_in[23];
    const float* wp0 = (const float*)d_in[24];
    const float* bp0 = (const float*)d_in[25];
    const float* wp1 = (const float*)d_in[26];
    const float* wp2 = (const float*)d_in[27];
    const float* wenv = (const float*)d_in[28];
    const float* benv = (const float*)d_in[29];
    float* out = (float*)d_out;

    char* ws = (char*)d_ws;
    float* nrm  = (float*)(ws + WS_NRM);
    ushort* pkw = (ushort*)(ws + WS_PK);
    const bool use_msg = (ws_size >= WS_REQ);
    int* counts = (int*)(ws + WS_CNT);
    int* offs   = (int*)(ws + WS_OFF);
    int* curs   = (int*)(ws + WS_CUR);
    int* eslot  = (int*)(ws + WS_EL);
    ushort* msg = (ushort*)(ws + WS_MSG);

    pack_k<<<(PKTOT + 255) / 256, 256, 0, stream>>>(w0s, w01, w02, wr11, wi11, wr12, wi12,
                                                    wr22, wi22, wenv, wp0, wp1, wp2, pkw);
    node_norm_k<<<(NN + 3) / 4, 256, 0, stream>>>(nf, g0n, b0n, g1n, g2n, nrm,
                                                  use_msg ? nullptr : out);
    if (use_msg) {
        zero_k<<<(NN + 255) / 256, 256, 0, stream>>>(counts);
        hist_k<<<(EE + 255) / 256, 256, 0, stream>>>(eidx, act, counts);
        scan_k<<<1, 256, 0, stream>>>(counts, offs, curs);
        scatter_k<<<(EE + 255) / 256, 256, 0, stream>>>(eidx, act, curs, eslot);
    }
    edge_k<<<EE / EPB, 512, 0, stream>>>(latents, efe, evec, eidx, act,
        use_msg ? eslot : nullptr,
        g0e, b0e, g1e, g2e, pkw, bp0, benv, nrm, use_msg ? msg : nullptr, out);
    if (use_msg) {
        gather_k<<<(NN + 3) / 4, 256, 0, stream>>>(msg, offs, counts, nf, out);
    }
}

// Round 9
// 285.269 us; speedup vs baseline: 2.0682x; 1.0718x over previous
//
#include <hip/hip_runtime.h>
#include <hip/hip_bf16.h>
#include <math.h>

#define NN 10000
#define EE 100000
#define EPB 16          // edges per block
#define AST 1000        // sA row stride (ushorts)
#define YSTH 456        // sY row stride (ushorts, bf16)
#define PSTA 40         // proj A-matrix row stride (ushorts)
#define PSTP 36         // sP row stride (floats)
#define MST 296         // msg staging row stride (ushorts)
#define STG0 10368      // staging base offset within sA (ushorts) = 20736 B

// staged-input segment offsets within an sA row (ushort index)
#define SEG0 0
#define SEGP1 288
#define SEGM1 480
#define SEGP2 672
#define SEGM2 768
#define SEGL 864

// sY per-edge layout (bf16)
#define Y0o   0
#define Y10o  96
#define Y20o  128
#define Y1Po  160
#define Y1Mo  192
#define Y2P1o 224
#define Y2M1o 256
#define Y2P2o 288
#define Y2M2o 320
#define WENVo 352

// packed-weight region offsets (ushort index)
#define PK1 0
#define PK2 46080
#define PK3 95232
#define PK4 107520
#define PKP 119808
#define PKTOT 122880

// workspace layout (bytes)
#define WS_NRM 0
#define WS_PK  11520000
#define WS_CNT 11765760
#define WS_OFF 11831296
#define WS_CUR 11896832
#define WS_EL  11962368
#define WS_MSG 12486656
#define WS_REQ (WS_MSG + (size_t)EE*288*2)

#define SQ3F  1.7320508075688772f
#define S0F   0.05892556509887896f
#define S1F   0.07216878364870323f
#define S2F   0.10206207261596575f
#define SEF   0.08838834764831845f
#define SCF   0.17677669529663687f
#define COLDF 0.8944271909999159f
#define COEFF 0.1414213562373095f

typedef __attribute__((ext_vector_type(8))) short bf16x8;
typedef __attribute__((ext_vector_type(4))) float f32x4;

__device__ __forceinline__ ushort f2bf(float f) {
    __hip_bfloat16 h = __float2bfloat16(f);
    return __builtin_bit_cast(unsigned short, h);
}
__device__ __forceinline__ float bf2f(ushort u) {
    union { unsigned u; float f; } v; v.u = (unsigned)u << 16; return v.f;
}
__device__ __forceinline__ float fsig(float x) {
    return __builtin_amdgcn_rcpf(1.f + __expf(-x));
}

__device__ __forceinline__ int planar(int k) {
    if (k < 32) return k;
    if (k < 128) { int c = (k - 32) / 3, m = (k - 32) % 3; return 32 + 32*m + c; }
    int c = (k - 128) / 5, m = (k - 128) % 5; return 128 + 32*m + c;
}

// ---------------- weight pre-pack ----------------
__global__ __launch_bounds__(256) void pack_k(
    const float* __restrict__ w0s, const float* __restrict__ w01, const float* __restrict__ w02,
    const float* __restrict__ wr11, const float* __restrict__ wi11,
    const float* __restrict__ wr12, const float* __restrict__ wi12,
    const float* __restrict__ wr22, const float* __restrict__ wi22,
    const float* __restrict__ wenv,
    const float* __restrict__ wp0, const float* __restrict__ wp1, const float* __restrict__ wp2,
    ushort* __restrict__ pk)
{
    int i = blockIdx.x * 256 + threadIdx.x;
    if (i >= PKTOT) return;
    float val;
    if (i < PK2) {
        int idx = i - PK1;
        int tile = idx / 4608, rem = idx % 4608;
        int chunk = rem / 512, rem2 = rem % 512;
        int lane = rem2 / 8, j = rem2 % 8;
        int col = tile * 16 + (lane & 15);
        int k = chunk * 32 + (lane >> 4) * 8 + j;
        if (col < 96)       val = w0s[col * 288 + k];
        else if (col < 128) val = w01[(col - 96) * 288 + k];
        else                val = w02[(col - 128) * 288 + k];
    } else if (i < PK3) {
        int idx = i - PK2;
        int tile = idx / 6144, rem = idx % 6144;
        int chunk = rem / 512, rem2 = rem % 512;
        int lane = rem2 / 8, j = rem2 % 8;
        int col = tile * 16 + (lane & 15);
        int k = chunk * 32 + (lane >> 4) * 8 + j;
        int grp = col >> 5, c = col & 31;
        if (k < 192) {
            val = (grp == 0) ? wr11[c*192 + k] : (grp == 1) ? wi11[c*192 + k]
                : (grp == 2) ? wr12[c*192 + k] : wi12[c*192 + k];
        } else {
            int kk = k - 192;
            val = (grp == 0) ? -wi11[c*192 + kk] : (grp == 1) ? wr11[c*192 + kk]
                : (grp == 2) ? -wi12[c*192 + kk] : wr12[c*192 + kk];
        }
    } else if (i < PK4) {
        int idx = i - PK3;
        int tile = idx / 3072, rem = idx % 3072;
        int chunk = rem / 512, rem2 = rem % 512;
        int lane = rem2 / 8, j = rem2 % 8;
        int col = tile * 16 + (lane & 15);
        int k = chunk * 32 + (lane >> 4) * 8 + j;
        int grp = col >> 5, c = col & 31;
        if (k < 96) val = grp ? wi22[c*96 + k] : wr22[c*96 + k];
        else        val = grp ? wr22[c*96 + k - 96] : -wi22[c*96 + k - 96];
    } else if (i < PKP) {
        int idx = i - PK4;
        int tile = idx / 2048, rem = idx % 2048;
        int chunk = rem / 512, rem2 = rem % 512;
        int lane = rem2 / 8, j = rem2 % 8;
        int col = tile * 16 + (lane & 15);
        int k = chunk * 32 + (lane >> 4) * 8 + j;
        val = wenv[col * 128 + k];
    } else {
        int idx = i - PKP;
        int wpi = idx / 1024, rem = idx % 1024;
        int ct = rem / 512, rem2 = rem % 512;
        int lane = rem2 / 8, j = rem2 % 8;
        int col = ct * 16 + (lane & 15);
        int k = (lane >> 4) * 8 + j;
        const float* w = (wpi == 0) ? wp0 : (wpi == 1) ? wp1 : wp2;
        val = w[col * 32 + k];
    }
    pk[i] = f2bf(val);
}

// ---------------- node SLN -> planar nrm ----------------
__global__ __launch_bounds__(256) void node_norm_k(
    const float* __restrict__ nf,
    const float* __restrict__ g0, const float* __restrict__ b0,
    const float* __restrict__ g1, const float* __restrict__ g2,
    float* __restrict__ nrm, float* __restrict__ out)
{
    int row = blockIdx.x * 4 + (threadIdx.x >> 6);
    if (row >= NN) return;
    int lane = threadIdx.x & 63;
    const float* r = nf + (size_t)row * 288;
    float v0 = r[lane];
    float v1 = r[lane + 64];
    float v2 = r[lane + 128];
    float v3 = r[lane + 192];
    float v4 = (lane < 32) ? r[lane + 256] : 0.f;
    float s0 = 0.f, s0q = 0.f, q1 = 0.f, q2 = 0.f;
    if (lane < 32) { s0 = v0; s0q = v0*v0; } else { q1 = v0*v0; }
    q1 += v1*v1;
    q2 += v2*v2 + v3*v3 + v4*v4;
#pragma unroll
    for (int m = 1; m < 64; m <<= 1) {
        s0  += __shfl_xor(s0, m);
        s0q += __shfl_xor(s0q, m);
        q1  += __shfl_xor(q1, m);
        q2  += __shfl_xor(q2, m);
    }
    float mu  = s0 * (1.f/32.f);
    float var = s0q * (1.f/32.f) - mu*mu;
    float rs0 = rsqrtf(var + 1e-8f);
    float rv  = 0.5f * (q1 * (1.f/96.f) + q2 * (1.f/160.f));
    float rs  = rsqrtf(rv + 1e-8f);
    float* nr = nrm + (size_t)row * 288;
    {
        float res;
        if (lane < 32) res = (v0 - mu) * rs0 * g0[lane] + b0[lane];
        else { int c = (lane - 32) / 3; res = v0 * rs * g1[c]; }
        nr[planar(lane)] = res;
    }
    { int k = lane + 64;  int c = (k - 32) / 3;  nr[planar(k)] = v1 * rs * g1[c]; }
    { int k = lane + 128; int c = (k - 128) / 5; nr[planar(k)] = v2 * rs * g2[c]; }
    { int k = lane + 192; int c = (k - 128) / 5; nr[planar(k)] = v3 * rs * g2[c]; }
    if (lane < 32) { int k = lane + 256; int c = (k - 128) / 5; nr[planar(k)] = v4 * rs * g2[c]; }
    if (out) {
        float* orow = out + (size_t)row * 288;
        orow[lane]       = COLDF * v0;
        orow[lane + 64]  = COLDF * v1;
        orow[lane + 128] = COLDF * v2;
        orow[lane + 192] = COLDF * v3;
        if (lane < 32) orow[lane + 256] = COLDF * v4;
    }
}

// ---------------- CSR build ----------------
__global__ __launch_bounds__(256) void zero_k(int* __restrict__ counts) {
    int i = blockIdx.x * 256 + threadIdx.x;
    if (i < NN) counts[i] = 0;
}
__global__ __launch_bounds__(256) void hist_k(
    const int* __restrict__ eidx, const int* __restrict__ act, int* __restrict__ counts) {
    int e = blockIdx.x * 256 + threadIdx.x;
    if (e >= EE) return;
    atomicAdd(&counts[eidx[act[e]]], 1);
}
__global__ __launch_bounds__(256) void scan_k(
    const int* __restrict__ counts, int* __restrict__ offs, int* __restrict__ curs) {
    __shared__ int sbuf[256];
    __shared__ int scarry;
    if (threadIdx.x == 0) scarry = 0;
    __syncthreads();
    for (int base = 0; base < NN; base += 256) {
        int i = base + threadIdx.x;
        int v = (i < NN) ? counts[i] : 0;
        sbuf[threadIdx.x] = v;
        __syncthreads();
        for (int off = 1; off < 256; off <<= 1) {
            int t = (threadIdx.x >= off) ? sbuf[threadIdx.x - off] : 0;
            __syncthreads();
            sbuf[threadIdx.x] += t;
            __syncthreads();
        }
        int excl = sbuf[threadIdx.x] - v;
        if (i < NN) { int o = scarry + excl; offs[i] = o; curs[i] = o; }
        __syncthreads();
        if (threadIdx.x == 255) scarry += sbuf[255];
        __syncthreads();
    }
}
__global__ __launch_bounds__(256) void scatter_k(
    const int* __restrict__ eidx, const int* __restrict__ act,
    int* __restrict__ curs, int* __restrict__ eslot) {
    int e = blockIdx.x * 256 + threadIdx.x;
    if (e >= EE) return;
    int pos = atomicAdd(&curs[eidx[act[e]]], 1);
    eslot[e] = pos;
}

// ---------------- gather ----------------
__global__ __launch_bounds__(256) void gather_k(
    const ushort* __restrict__ msg, const int* __restrict__ offs,
    const int* __restrict__ counts,
    const float* __restrict__ nf, float* __restrict__ out)
{
    int node = blockIdx.x * 4 + (threadIdx.x >> 6);
    if (node >= NN) return;
    int lane = threadIdx.x & 63;
    int start = offs[node], cnt = counts[node];
    float a0 = 0.f, a1 = 0.f, a2 = 0.f, a3 = 0.f, a4 = 0.f;
    const ushort* mr = msg + (size_t)start * 288;
    for (int i = 0; i < cnt; ++i, mr += 288) {
        a0 += bf2f(mr[lane]);
        a1 += bf2f(mr[lane + 64]);
        a2 += bf2f(mr[lane + 128]);
        a3 += bf2f(mr[lane + 192]);
        if (lane < 32) a4 += bf2f(mr[lane + 256]);
    }
    const float* r = nf + (size_t)node * 288;
    float* o = out + (size_t)node * 288;
    o[lane]       = COLDF * r[lane]       + COEFF * a0;
    o[lane + 64]  = COLDF * r[lane + 64]  + COEFF * a1;
    o[lane + 128] = COLDF * r[lane + 128] + COEFF * a2;
    o[lane + 192] = COLDF * r[lane + 192] + COEFF * a3;
    if (lane < 32) o[lane + 256] = COLDF * r[lane + 256] + COEFF * a4;
}

// ---------------- fused edge kernel: 512 threads / 16 edges ----------------
__global__ __launch_bounds__(512, 6) void edge_k(
    const float* __restrict__ lat, const float* __restrict__ ef,
    const float* __restrict__ evec,
    const int* __restrict__ eidx, const int* __restrict__ act,
    const int* __restrict__ eslot,
    const float* __restrict__ g0e, const float* __restrict__ b0e,
    const float* __restrict__ g1e, const float* __restrict__ g2e,
    const ushort* __restrict__ pk,
    const float* __restrict__ bp0, const float* __restrict__ benv,
    const float* __restrict__ nrm, ushort* __restrict__ msg, float* __restrict__ out)
{
    __shared__ __align__(16) ushort sA[EPB * AST];   // staged A; reused: projA -> sP(f32) + msg staging
    __shared__ __align__(16) ushort sY[EPB * YSTH];
    __shared__ float sD1[EPB][12];
    __shared__ float sD2[EPB][28];
    __shared__ int sAe[EPB], sCtr[EPB], sNbr[EPB], sSlot[EPB];

    const int tid = threadIdx.x;
    const int wv = tid >> 6, lane = tid & 63;

    // ---------------- prologue: indices + frame + analytic l=2 Wigner (16 threads, once) ----------------
    if (tid < EPB) {
        int ae = act[blockIdx.x * EPB + tid];
        sAe[tid] = ae;
        sCtr[tid] = eidx[ae];
        sNbr[tid] = eidx[EE + ae];
        sSlot[tid] = eslot ? eslot[blockIdx.x * EPB + tid] : 0;

        float vx = evec[3*ae], vy = evec[3*ae+1], vz = evec[3*ae+2];
        float nnv = fmaxf(sqrtf(vx*vx + vy*vy + vz*vz), 1e-9f);
        float nx = vx/nnv, ny = vy/nnv, nz = vz/nnv;
        float ax, az;
        if (fabsf(nx) < 0.9f) { ax = 1.f; az = 0.f; } else { ax = 0.f; az = 1.f; }
        float adn = ax*nx + az*nz;
        float ux = ax - adn*nx, uy = -adn*ny, uz = az - adn*nz;
        float un = fmaxf(sqrtf(ux*ux + uy*uy + uz*uz), 1e-9f);
        ux /= un; uy /= un; uz /= un;
        float wx = uy*nz - uz*ny, wy = uz*nx - ux*nz, wz = ux*ny - uy*nx;

        sD1[tid][0] = ux; sD1[tid][1] = uy; sD1[tid][2] = uz;
        sD1[tid][3] = nx; sD1[tid][4] = ny; sD1[tid][5] = nz;
        sD1[tid][6] = wx; sD1[tid][7] = wy; sD1[tid][8] = wz;

        float d2[5][5];
        d2[0][0] = wz*ux + uz*wx;  d2[0][1] = wx*uy + ux*wy;  d2[0][2] = SQ3F*wy*uy;
        d2[0][3] = wy*uz + uy*wz;  d2[0][4] = wz*uz - wx*ux;
        d2[1][0] = uz*nx + nz*ux;  d2[1][1] = ux*ny + nx*uy;  d2[1][2] = SQ3F*uy*ny;
        d2[1][3] = uy*nz + ny*uz;  d2[1][4] = uz*nz - ux*nx;
        d2[2][0] = SQ3F*nz*nx;     d2[2][1] = SQ3F*nx*ny;     d2[2][2] = 1.5f*ny*ny - 0.5f;
        d2[2][3] = SQ3F*ny*nz;     d2[2][4] = 0.5f*SQ3F*(nz*nz - nx*nx);
        d2[3][0] = nz*wx + wz*nx;  d2[3][1] = nx*wy + wx*ny;  d2[3][2] = SQ3F*ny*wy;
        d2[3][3] = ny*wz + wy*nz;  d2[3][4] = nz*wz - nx*wx;
        d2[4][0] = wz*wx - uz*ux;  d2[4][1] = wx*wy - ux*uy;  d2[4][2] = 0.5f*SQ3F*(wy*wy - uy*uy);
        d2[4][3] = wy*wz - uy*uz;  d2[4][4] = 0.5f*(wz*wz - uz*uz - wx*wx + ux*ux);
#pragma unroll
        for (int n = 0; n < 5; ++n)
#pragma unroll
            for (int m = 0; m < 5; ++m) sD2[tid][5*n + m] = d2[n][m];
    }
    __syncthreads();

    // ---------------- prep part 1: wave per edge, 2 iterations (SLN + staging only) ----------------
    for (int it = 0; it < 2; ++it) {
        const int e = it * 8 + wv;
        const int ae = sAe[e];
        const int ctr = sCtr[e], nbr = sNbr[e];
        ushort* row = sA + e * AST;
        ushort* sEb = sY + e * YSTH;
        const float* efr = ef + (size_t)ae * 288;

        float ev0 = efr[lane];
        float ev1 = efr[lane + 64];
        float ev2 = efr[lane + 128];
        float ev3 = efr[lane + 192];
        float ev4 = (lane < 32) ? efr[lane + 256] : 0.f;
        float s0 = 0.f, s0q = 0.f, q1 = 0.f, q2 = 0.f;
        if (lane < 32) { s0 = ev0; s0q = ev0*ev0; } else { q1 = ev0*ev0; }
        q1 += ev1*ev1;
        q2 += ev2*ev2 + ev3*ev3 + ev4*ev4;
#pragma unroll
        for (int m = 1; m < 64; m <<= 1) {
            s0  += __shfl_xor(s0, m);
            s0q += __shfl_xor(s0q, m);
            q1  += __shfl_xor(q1, m);
            q2  += __shfl_xor(q2, m);
        }
        float mu  = s0 * (1.f/32.f);
        float rs0 = rsqrtf(s0q*(1.f/32.f) - mu*mu + 1e-8f);
        float rs  = rsqrtf(0.5f*(q1*(1.f/96.f) + q2*(1.f/160.f)) + 1e-8f);

        if (lane >= 32) { int c = (lane-32)/3, m = (lane-32)%3; sEb[32 + 32*m + c] = f2bf(ev0 * rs * g1e[c]); }
        { int k = lane+64;  int c = (k-32)/3,  m = (k-32)%3;  sEb[32 + 32*m + c]  = f2bf(ev1 * rs * g1e[c]); }
        { int k = lane+128; int c = (k-128)/5, m = (k-128)%5; sEb[128 + 32*m + c] = f2bf(ev2 * rs * g2e[c]); }
        { int k = lane+192; int c = (k-128)/5, m = (k-128)%5; sEb[128 + 32*m + c] = f2bf(ev3 * rs * g2e[c]); }
        if (lane < 32) { int k = lane+256; int c = (k-128)/5, m = (k-128)%5; sEb[128 + 32*m + c] = f2bf(ev4 * rs * g2e[c]); }

        if (lane < 32) {
            row[SEG0 + 32 + lane] = f2bf((ev0 - mu) * rs0 * g0e[lane] + b0e[lane]);
            row[SEG0 + lane]      = f2bf(nrm[(size_t)ctr*288 + lane]);
            row[SEG0 + 64 + lane] = f2bf(nrm[(size_t)nbr*288 + lane]);
        }
        {
            const float* lr = lat + (size_t)ae * 128;
            row[SEGL + lane]      = f2bf(lr[lane]);
            row[SEGL + 64 + lane] = f2bf(lr[lane + 64]);
        }
    }
    __syncthreads();

    // ---------------- prep part 2: uniform rotate, thread = (edge, channel) ----------------
    {
        const int re = tid >> 5;        // edge 0..15
        const int rc = tid & 31;        // channel within group
        const float* bc = nrm + (size_t)sCtr[re] * 288;
        const float* bn = nrm + (size_t)sNbr[re] * 288;
        float c1v[3], c2v[5], n1v[3], n2v[5];
#pragma unroll
        for (int m = 0; m < 3; ++m) { c1v[m] = bc[32 + 32*m + rc]; n1v[m] = bn[32 + 32*m + rc]; }
#pragma unroll
        for (int m = 0; m < 5; ++m) { c2v[m] = bc[128 + 32*m + rc]; n2v[m] = bn[128 + 32*m + rc]; }
        float D1r[9], d2l[25];
#pragma unroll
        for (int i = 0; i < 9; ++i) D1r[i] = sD1[re][i];
#pragma unroll
        for (int i = 0; i < 25; ++i) d2l[i] = sD2[re][i];
        ushort* row = sA + re * AST;
        const ushort* sEb = sY + re * YSTH;
        float e1v[3], e2v[5];
#pragma unroll
        for (int m = 0; m < 3; ++m) e1v[m] = bf2f(sEb[32 + 32*m + rc]);
#pragma unroll
        for (int m = 0; m < 5; ++m) e2v[m] = bf2f(sEb[128 + 32*m + rc]);
#pragma unroll
        for (int p = 0; p < 3; ++p) {
            const int cc = rc + 32 * p;
            float x1v[3], x2v[5];
#pragma unroll
            for (int m = 0; m < 3; ++m) x1v[m] = (p == 0) ? c1v[m] : (p == 1) ? e1v[m] : n1v[m];
#pragma unroll
            for (int m = 0; m < 5; ++m) x2v[m] = (p == 0) ? c2v[m] : (p == 1) ? e2v[m] : n2v[m];
            float r0 = D1r[0]*x1v[0] + D1r[1]*x1v[1] + D1r[2]*x1v[2];
            float r1 = D1r[3]*x1v[0] + D1r[4]*x1v[1] + D1r[5]*x1v[2];
            float r2 = D1r[6]*x1v[0] + D1r[7]*x1v[1] + D1r[8]*x1v[2];
            float t[5];
#pragma unroll
            for (int m = 0; m < 5; ++m)
                t[m] = d2l[5*m+0]*x2v[0] + d2l[5*m+1]*x2v[1] + d2l[5*m+2]*x2v[2]
                     + d2l[5*m+3]*x2v[3] + d2l[5*m+4]*x2v[4];
            row[SEG0 + 96  + cc] = f2bf(r1);
            row[SEG0 + 192 + cc] = f2bf(t[2]);
            row[SEGP1 + cc]      = f2bf(r2);
            row[SEGP1 + 96 + cc] = f2bf(t[3]);
            row[SEGM1 + cc]      = f2bf(r0);
            row[SEGM1 + 96 + cc] = f2bf(t[1]);
            row[SEGP2 + cc]      = f2bf(t[4]);
            row[SEGM2 + cc]      = f2bf(t[0]);
        }
    }
    __syncthreads();

    // ---------------- MFMA GEMM phase: 28 tiles across 8 waves ----------------
    for (int t = wv; t < 28; t += 8) {
        int kbase, nch, yoff, pbase; float scale;
        if (t < 10)      { kbase = SEG0;  nch = 9;  yoff = t*16;          scale = S0F; pbase = PK1 + t*9*512; }
        else if (t < 18) { kbase = SEGP1; nch = 12; yoff = 160+(t-10)*16; scale = S1F; pbase = PK2 + (t-10)*12*512; }
        else if (t < 22) { kbase = SEGP2; nch = 6;  yoff = 288+(t-18)*16; scale = S2F; pbase = PK3 + (t-18)*6*512; }
        else             { kbase = SEGL;  nch = 4;  yoff = 352+(t-22)*16; scale = SEF; pbase = PK4 + (t-22)*4*512; }
        f32x4 acc = {0.f, 0.f, 0.f, 0.f};
        const ushort* pa = sA + (lane & 15) * AST + kbase + (lane >> 4) * 8;
        const ushort* pb = pk + pbase + lane * 8;
        for (int ch = 0; ch < nch; ++ch) {
            bf16x8 a = *reinterpret_cast<const bf16x8*>(pa + ch * 32);
            bf16x8 b = *reinterpret_cast<const bf16x8*>(pb + ch * 512);
            acc = __builtin_amdgcn_mfma_f32_16x16x32_bf16(a, b, acc, 0, 0, 0);
        }
        const int col = yoff + (lane & 15);
        const int r0 = (lane >> 4) * 4;
        float bv = (t >= 22) ? benv[col - 352] : 0.f;
#pragma unroll
        for (int j = 0; j < 4; ++j)
            sY[(r0 + j) * YSTH + col] = f2bf(acc[j] * scale + bv);
    }
    __syncthreads();

    // ---------------- stage 2a: gates, gated n-frame A-matrix (144 x 32, stride PSTA) ----------------
    const int e2 = tid & 15, c = tid >> 4;   // c in 0..31
    const ushort* yrow = sY + e2 * YSTH;
    {
        float y0v = bf2f(yrow[Y0o + c]);
        float scv = y0v * fsig(y0v);
        float gg1 = fsig(bf2f(yrow[Y0o + 32 + c]));
        float gg2 = fsig(bf2f(yrow[Y0o + 64 + c]));
        sA[(0   + e2)*PSTA + c] = f2bf(scv);
        sA[(16  + e2)*PSTA + c] = f2bf(bf2f(yrow[Y1Mo  + c]) * gg1);
        sA[(32  + e2)*PSTA + c] = f2bf(bf2f(yrow[Y10o  + c]) * gg1);
        sA[(48  + e2)*PSTA + c] = f2bf(bf2f(yrow[Y1Po  + c]) * gg1);
        sA[(64  + e2)*PSTA + c] = f2bf(bf2f(yrow[Y2M2o + c]) * gg2);
        sA[(80  + e2)*PSTA + c] = f2bf(bf2f(yrow[Y2M1o + c]) * gg2);
        sA[(96  + e2)*PSTA + c] = f2bf(bf2f(yrow[Y20o  + c]) * gg2);
        sA[(112 + e2)*PSTA + c] = f2bf(bf2f(yrow[Y2P1o + c]) * gg2);
        sA[(128 + e2)*PSTA + c] = f2bf(bf2f(yrow[Y2P2o + c]) * gg2);
    }
    __syncthreads();

    // ---------------- proj MFMA: 18 tiles (9 row x 2 col) across 8 waves ----------------
    f32x4 pacc[3];
#pragma unroll
    for (int q = 0; q < 3; ++q) {
        const int t = wv + 8*q;
        if (t < 18) {
            const int rt = t >> 1, ct = t & 1;
            const int wpi = (rt == 0) ? 0 : (rt < 4) ? 1 : 2;
            bf16x8 a = *reinterpret_cast<const bf16x8*>(sA + (rt*16 + (lane & 15))*PSTA + (lane >> 4)*8);
            bf16x8 b = *reinterpret_cast<const bf16x8*>(pk + PKP + wpi*1024 + ct*512 + lane*8);
            f32x4 z = {0.f, 0.f, 0.f, 0.f};
            pacc[q] = __builtin_amdgcn_mfma_f32_16x16x32_bf16(a, b, z, 0, 0, 0);
        }
    }
    __syncthreads();   // A reads done -> overwrite sA with sP (f32, stride PSTP)

    float* sPf = reinterpret_cast<float*>(sA);
#pragma unroll
    for (int q = 0; q < 3; ++q) {
        const int t = wv + 8*q;
        if (t < 18) {
            const int rt = t >> 1, ct = t & 1;
            const int col = ct*16 + (lane & 15);
#pragma unroll
            for (int j = 0; j < 4; ++j) {
                const int rw = rt*16 + (lane >> 4)*4 + j;
                sPf[rw*PSTP + col] = pacc[q][j];
            }
        }
    }
    __syncthreads();

    // ---------------- stage 2b: rotate-back + env gate -> LDS staging (or atomic fallback) ----------------
    const int d = c;
    {
        float wv0g = bf2f(yrow[WENVo + d]);
        float m0v = (sPf[e2*PSTP + d] * SCF + bp0[d]) * wv0g;

        float p1v[3], p2v[5];
#pragma unroll
        for (int m = 0; m < 3; ++m) p1v[m] = sPf[(16 + 16*m + e2)*PSTP + d];
#pragma unroll
        for (int m = 0; m < 5; ++m) p2v[m] = sPf[(64 + 16*m + e2)*PSTP + d];

        float wv1g = bf2f(yrow[WENVo + 32 + d]) * SCF;
        float wv2g = bf2f(yrow[WENVo + 64 + d]) * SCF;

        float o1[3], o2[5];
#pragma unroll
        for (int mm = 0; mm < 3; ++mm)
            o1[mm] = (sD1[e2][mm]*p1v[0] + sD1[e2][3+mm]*p1v[1] + sD1[e2][6+mm]*p1v[2]) * wv1g;
#pragma unroll
        for (int mm = 0; mm < 5; ++mm)
            o2[mm] = (sD2[e2][mm]*p2v[0] + sD2[e2][5+mm]*p2v[1] + sD2[e2][10+mm]*p2v[2]
                    + sD2[e2][15+mm]*p2v[3] + sD2[e2][20+mm]*p2v[4]) * wv2g;

        if (msg) {
            ushort* stg = sA + STG0 + e2 * MST;
            stg[d] = f2bf(m0v);
#pragma unroll
            for (int mm = 0; mm < 3; ++mm) stg[32 + 3*d + mm] = f2bf(o1[mm]);
#pragma unroll
            for (int mm = 0; mm < 5; ++mm) stg[128 + 5*d + mm] = f2bf(o2[mm]);
        } else {
            float* ob = out + (size_t)sCtr[e2] * 288;
            atomicAdd(ob + d, COEFF * m0v);
#pragma unroll
            for (int mm = 0; mm < 3; ++mm) atomicAdd(ob + 32 + 3*d + mm, COEFF * o1[mm]);
#pragma unroll
            for (int mm = 0; mm < 5; ++mm) atomicAdd(ob + 128 + 5*d + mm, COEFF * o2[mm]);
        }
    }
    __syncthreads();

    // ---------------- coalesced msg copy: 16 rows x 288 ushorts = 36 b128 chunks/row ----------------
    if (msg) {
        const int e = tid >> 5, j = tid & 31;
        const ushort* src = sA + STG0 + e * MST;
        ushort* dst = msg + (size_t)sSlot[e] * 288;
        *reinterpret_cast<bf16x8*>(dst + j*8) = *reinterpret_cast<const bf16x8*>(src + j*8);
        if (j < 4)
            *reinterpret_cast<bf16x8*>(dst + (j+32)*8) = *reinterpret_cast<const bf16x8*>(src + (j+32)*8);
    }
}

extern "C" void kernel_launch(void* const* d_in, const int* in_sizes, int n_in,
                              void* d_out, int out_size, void* d_ws, size_t ws_size,
                              hipStream_t stream)
{
    const float* latents = (const float*)d_in[0];
    const float* nf      = (const float*)d_in[1];
    const float* efe     = (const float*)d_in[2];
    const float* evec    = (const float*)d_in[3];
    const int*   eidx    = (const int*)d_in[5];
    const int*   act     = (const int*)d_in[6];
    const float* g0n = (const float*)d_in[7];
    const float* b0n = (const float*)d_in[8];
    const float* g1n = (const float*)d_in[9];
    const float* g2n = (const float*)d_in[10];
    const float* g0e = (const float*)d_in[11];
    const float* b0e = (const float*)d_in[12];
    const float* g1e = (const float*)d_in[13];
    const float* g2e = (const float*)d_in[14];
    const float* w0s = (const float*)d_in[15];
    const float* w01 = (const float*)d_in[16];
    const float* w02 = (const float*)d_in[17];
    const float* wr11 = (const float*)d_in[18];
    const float* wi11 = (const float*)d_in[19];
    const float* wr12 = (const float*)d_in[20];
    const float* wi12 = (const float*)d_in[21];
    const float* wr22 = (const float*)d_in[22];
    const float* wi22 = (const float*)d_in[23];
    const float* wp0 = (const float*)d_in[24];
    const float* bp0 = (const float*)d_in[25];
    const float* wp1 = (const float*)d_in[26];
    const float* wp2 = (const float*)d_in[27];
    const float* wenv = (const float*)d_in[28];
    const float* benv = (const float*)d_in[29];
    float* out = (float*)d_out;

    char* ws = (char*)d_ws;
    float* nrm  = (float*)(ws + WS_NRM);
    ushort* pkw = (ushort*)(ws + WS_PK);
    const bool use_msg = (ws_size >= WS_REQ);
    int* counts = (int*)(ws + WS_CNT);
    int* offs   = (int*)(ws + WS_OFF);
    int* curs   = (int*)(ws + WS_CUR);
    int* eslot  = (int*)(ws + WS_EL);
    ushort* msg = (ushort*)(ws + WS_MSG);

    pack_k<<<(PKTOT + 255) / 256, 256, 0, stream>>>(w0s, w01, w02, wr11, wi11, wr12, wi12,
                                                    wr22, wi22, wenv, wp0, wp1, wp2, pkw);
    node_norm_k<<<(NN + 3) / 4, 256, 0, stream>>>(nf, g0n, b0n, g1n, g2n, nrm,
                                                  use_msg ? nullptr : out);
    if (use_msg) {
        zero_k<<<(NN + 255) / 256, 256, 0, stream>>>(counts);
        hist_k<<<(EE + 255) / 256, 256, 0, stream>>>(eidx, act, counts);
        scan_k<<<1, 256, 0, stream>>>(counts, offs, curs);
        scatter_k<<<(EE + 255) / 256, 256, 0, stream>>>(eidx, act, curs, eslot);
    }
    edge_k<<<EE / EPB, 512, 0, stream>>>(latents, efe, evec, eidx, act,
        use_msg ? eslot : nullptr,
        g0e, b0e, g1e, g2e, pkw, bp0, benv, nrm, use_msg ? msg : nullptr, out);
    if (use_msg) {
        gather_k<<<(NN + 3) / 4, 256, 0, stream>>>(msg, offs, counts, nf, out);
    }
}

// Round 10
// 232.109 us; speedup vs baseline: 2.5418x; 1.2290x over previous
//
#include <hip/hip_runtime.h>
#include <hip/hip_bf16.h>
#include <math.h>

#define NN 10000
#define EE 100000
#define EPB 16          // edges per block
#define AST 992         // sA row stride (ushorts), 1984 B (16B aligned)
#define PA0 480         // projA base within row (ushort)

// staged-input segment offsets within an sA row (ushort index)
#define SEG0 0
#define SEGP1 288
#define SEGM1 480
#define SEGP2 672
#define SEGM2 768
#define SEGL 864

// Y layout (absolute x within row, bf16, XOR-swizzled by edge)
#define Y0o   0
#define Y10o  96
#define Y20o  128
#define Y1Po  160
#define Y1Mo  192
#define Y2P1o 224
#define Y2M1o 256
#define Y2P2o 288
#define Y2M2o 320
#define WENVo 352

// packed-weight region offsets (ushort index)
#define PK1 0
#define PK2 46080
#define PK3 95232
#define PK4 107520
#define PKP 119808
#define PKTOT 122880

// workspace layout (bytes)
#define WS_NRM 0
#define WS_PK  11520000
#define WS_CNT 11765760
#define WS_OFF 11831296
#define WS_CUR 11896832
#define WS_EL  11962368
#define WS_MSG 12486656
#define WS_REQ (WS_MSG + (size_t)EE*288*2)

#define SQ3F  1.7320508075688772f
#define S0F   0.05892556509887896f
#define S1F   0.07216878364870323f
#define S2F   0.10206207261596575f
#define SEF   0.08838834764831845f
#define SCF   0.17677669529663687f
#define COLDF 0.8944271909999159f
#define COEFF 0.1414213562373095f

// fused init kernel block ranges
#define NNB 2500                  // node_norm blocks (4 rows each)
#define PKB ((PKTOT + 255) / 256)
#define HSB ((EE + 255) / 256)

typedef __attribute__((ext_vector_type(8))) short bf16x8;
typedef __attribute__((ext_vector_type(4))) float f32x4;

__device__ __forceinline__ ushort f2bf(float f) {
    __hip_bfloat16 h = __float2bfloat16(f);
    return __builtin_bit_cast(unsigned short, h);
}
__device__ __forceinline__ float bf2f(ushort u) {
    union { unsigned u; float f; } v; v.u = (unsigned)u << 16; return v.f;
}
__device__ __forceinline__ float fsig(float x) {
    return __builtin_amdgcn_rcpf(1.f + __expf(-x));
}
__device__ __forceinline__ int planar(int k) {
    if (k < 32) return k;
    if (k < 128) { int c = (k - 32) / 3, m = (k - 32) % 3; return 32 + 32*m + c; }
    int c = (k - 128) / 5, m = (k - 128) % 5; return 128 + 32*m + c;
}

// ---------------- fused init: node_norm | pack | hist ----------------
__global__ __launch_bounds__(256) void init_k(
    const float* __restrict__ nf,
    const float* __restrict__ g0, const float* __restrict__ b0,
    const float* __restrict__ g1, const float* __restrict__ g2,
    float* __restrict__ nrm, float* __restrict__ out,
    const float* __restrict__ w0s, const float* __restrict__ w01, const float* __restrict__ w02,
    const float* __restrict__ wr11, const float* __restrict__ wi11,
    const float* __restrict__ wr12, const float* __restrict__ wi12,
    const float* __restrict__ wr22, const float* __restrict__ wi22,
    const float* __restrict__ wenv,
    const float* __restrict__ wp0, const float* __restrict__ wp1, const float* __restrict__ wp2,
    ushort* __restrict__ pk,
    const int* __restrict__ eidx, const int* __restrict__ act, int* __restrict__ counts)
{
    const int bid = blockIdx.x;
    if (bid < NNB) {
        // ---- node SLN -> planar nrm ----
        int row = bid * 4 + (threadIdx.x >> 6);
        if (row >= NN) return;
        int lane = threadIdx.x & 63;
        const float* r = nf + (size_t)row * 288;
        float v0 = r[lane];
        float v1 = r[lane + 64];
        float v2 = r[lane + 128];
        float v3 = r[lane + 192];
        float v4 = (lane < 32) ? r[lane + 256] : 0.f;
        float s0 = 0.f, s0q = 0.f, q1 = 0.f, q2 = 0.f;
        if (lane < 32) { s0 = v0; s0q = v0*v0; } else { q1 = v0*v0; }
        q1 += v1*v1;
        q2 += v2*v2 + v3*v3 + v4*v4;
#pragma unroll
        for (int m = 1; m < 64; m <<= 1) {
            s0  += __shfl_xor(s0, m);
            s0q += __shfl_xor(s0q, m);
            q1  += __shfl_xor(q1, m);
            q2  += __shfl_xor(q2, m);
        }
        float mu  = s0 * (1.f/32.f);
        float rs0 = rsqrtf(s0q*(1.f/32.f) - mu*mu + 1e-8f);
        float rs  = rsqrtf(0.5f*(q1*(1.f/96.f) + q2*(1.f/160.f)) + 1e-8f);
        float* nr = nrm + (size_t)row * 288;
        {
            float res;
            if (lane < 32) res = (v0 - mu) * rs0 * g0[lane] + b0[lane];
            else { int c = (lane - 32) / 3; res = v0 * rs * g1[c]; }
            nr[planar(lane)] = res;
        }
        { int k = lane + 64;  int c = (k - 32) / 3;  nr[planar(k)] = v1 * rs * g1[c]; }
        { int k = lane + 128; int c = (k - 128) / 5; nr[planar(k)] = v2 * rs * g2[c]; }
        { int k = lane + 192; int c = (k - 128) / 5; nr[planar(k)] = v3 * rs * g2[c]; }
        if (lane < 32) { int k = lane + 256; int c = (k - 128) / 5; nr[planar(k)] = v4 * rs * g2[c]; }
        if (out) {
            float* orow = out + (size_t)row * 288;
            orow[lane]       = COLDF * v0;
            orow[lane + 64]  = COLDF * v1;
            orow[lane + 128] = COLDF * v2;
            orow[lane + 192] = COLDF * v3;
            if (lane < 32) orow[lane + 256] = COLDF * v4;
        }
    } else if (bid < NNB + PKB) {
        // ---- weight pre-pack ----
        int i = (bid - NNB) * 256 + threadIdx.x;
        if (i >= PKTOT) return;
        float val;
        if (i < PK2) {
            int idx = i - PK1;
            int tile = idx / 4608, rem = idx % 4608;
            int chunk = rem / 512, rem2 = rem % 512;
            int lane = rem2 / 8, j = rem2 % 8;
            int col = tile * 16 + (lane & 15);
            int k = chunk * 32 + (lane >> 4) * 8 + j;
            if (col < 96)       val = w0s[col * 288 + k];
            else if (col < 128) val = w01[(col - 96) * 288 + k];
            else                val = w02[(col - 128) * 288 + k];
        } else if (i < PK3) {
            int idx = i - PK2;
            int tile = idx / 6144, rem = idx % 6144;
            int chunk = rem / 512, rem2 = rem % 512;
            int lane = rem2 / 8, j = rem2 % 8;
            int col = tile * 16 + (lane & 15);
            int k = chunk * 32 + (lane >> 4) * 8 + j;
            int grp = col >> 5, c = col & 31;
            if (k < 192) {
                val = (grp == 0) ? wr11[c*192 + k] : (grp == 1) ? wi11[c*192 + k]
                    : (grp == 2) ? wr12[c*192 + k] : wi12[c*192 + k];
            } else {
                int kk = k - 192;
                val = (grp == 0) ? -wi11[c*192 + kk] : (grp == 1) ? wr11[c*192 + kk]
                    : (grp == 2) ? -wi12[c*192 + kk] : wr12[c*192 + kk];
            }
        } else if (i < PK4) {
            int idx = i - PK3;
            int tile = idx / 3072, rem = idx % 3072;
            int chunk = rem / 512, rem2 = rem % 512;
            int lane = rem2 / 8, j = rem2 % 8;
            int col = tile * 16 + (lane & 15);
            int k = chunk * 32 + (lane >> 4) * 8 + j;
            int grp = col >> 5, c = col & 31;
            if (k < 96) val = grp ? wi22[c*96 + k] : wr22[c*96 + k];
            else        val = grp ? wr22[c*96 + k - 96] : -wi22[c*96 + k - 96];
        } else if (i < PKP) {
            int idx = i - PK4;
            int tile = idx / 2048, rem = idx % 2048;
            int chunk = rem / 512, rem2 = rem % 512;
            int lane = rem2 / 8, j = rem2 % 8;
            int col = tile * 16 + (lane & 15);
            int k = chunk * 32 + (lane >> 4) * 8 + j;
            val = wenv[col * 128 + k];
        } else {
            int idx = i - PKP;
            int wpi = idx / 1024, rem = idx % 1024;
            int ct = rem / 512, rem2 = rem % 512;
            int lane = rem2 / 8, j = rem2 % 8;
            int col = ct * 16 + (lane & 15);
            int k = (lane >> 4) * 8 + j;
            const float* w = (wpi == 0) ? wp0 : (wpi == 1) ? wp1 : wp2;
            val = w[col * 32 + k];
        }
        pk[i] = f2bf(val);
    } else {
        // ---- hist (counts pre-zeroed by memset) ----
        int e = (bid - NNB - PKB) * 256 + threadIdx.x;
        if (e >= EE) return;
        atomicAdd(&counts[eidx[act[e]]], 1);
    }
}

// ---------------- single-pass scan: 1024 threads x 10 elems ----------------
__global__ __launch_bounds__(1024) void scan_k(
    const int* __restrict__ counts, int* __restrict__ offs, int* __restrict__ curs)
{
    const int tid = threadIdx.x;
    const int base = tid * 10;
    int v[10]; int s = 0;
#pragma unroll
    for (int j = 0; j < 10; ++j) {
        int i = base + j;
        int c = (i < NN) ? counts[i] : 0;
        v[j] = s; s += c;
    }
    const int lane = tid & 63, wv = tid >> 6;
    int inc = s;
#pragma unroll
    for (int off = 1; off < 64; off <<= 1) {
        int t = __shfl_up(inc, off);
        if (lane >= off) inc += t;
    }
    __shared__ int wsum[16], wbase[16];
    if (lane == 63) wsum[wv] = inc;
    __syncthreads();
    if (tid == 0) {
        int acc = 0;
#pragma unroll
        for (int i = 0; i < 16; ++i) { int t = wsum[i]; wbase[i] = acc; acc += t; }
    }
    __syncthreads();
    const int texcl = wbase[wv] + inc - s;
#pragma unroll
    for (int j = 0; j < 10; ++j) {
        int i = base + j;
        if (i < NN) { int o = texcl + v[j]; offs[i] = o; curs[i] = o; }
    }
}

__global__ __launch_bounds__(256) void scatter_k(
    const int* __restrict__ eidx, const int* __restrict__ act,
    int* __restrict__ curs, int* __restrict__ eslot) {
    int e = blockIdx.x * 256 + threadIdx.x;
    if (e >= EE) return;
    int pos = atomicAdd(&curs[eidx[act[e]]], 1);
    eslot[e] = pos;
}

// ---------------- gather: out = c_old*nf + c_new * sum(msg rows) ----------------
__global__ __launch_bounds__(256) void gather_k(
    const ushort* __restrict__ msg, const int* __restrict__ offs,
    const int* __restrict__ counts,
    const float* __restrict__ nf, float* __restrict__ out)
{
    int node = blockIdx.x * 4 + (threadIdx.x >> 6);
    if (node >= NN) return;
    int lane = threadIdx.x & 63;
    int start = offs[node], cnt = counts[node];
    float a0x = 0.f, a0y = 0.f, a1x = 0.f, a1y = 0.f, a2x = 0.f, a2y = 0.f;
    const uint* mu = (const uint*)(msg + (size_t)start * 288);
    for (int i = 0; i < cnt; ++i, mu += 144) {
        uint u0 = mu[lane];
        uint u1 = mu[lane + 64];
        uint u2 = (lane < 16) ? mu[lane + 128] : 0u;
        a0x += bf2f((ushort)u0); a0y += bf2f((ushort)(u0 >> 16));
        a1x += bf2f((ushort)u1); a1y += bf2f((ushort)(u1 >> 16));
        a2x += bf2f((ushort)u2); a2y += bf2f((ushort)(u2 >> 16));
    }
    const float2* r2 = (const float2*)(nf + (size_t)node * 288);
    float2* o2 = (float2*)(out + (size_t)node * 288);
    float2 r;
    r = r2[lane];
    o2[lane]      = make_float2(COLDF*r.x + COEFF*a0x, COLDF*r.y + COEFF*a0y);
    r = r2[lane + 64];
    o2[lane + 64] = make_float2(COLDF*r.x + COEFF*a1x, COLDF*r.y + COEFF*a1y);
    if (lane < 16) {
        r = r2[lane + 128];
        o2[lane + 128] = make_float2(COLDF*r.x + COEFF*a2x, COLDF*r.y + COEFF*a2y);
    }
}

// ---------------- fused edge kernel: 512 threads / 16 edges, 34.6 KB LDS ----------------
__global__ __launch_bounds__(512, 8) void edge_k(
    const float* __restrict__ lat, const float* __restrict__ ef,
    const float* __restrict__ evec,
    const int* __restrict__ eidx, const int* __restrict__ act,
    const int* __restrict__ eslot,
    const float* __restrict__ g0e, const float* __restrict__ b0e,
    const float* __restrict__ g1e, const float* __restrict__ g2e,
    const ushort* __restrict__ pk,
    const float* __restrict__ bp0, const float* __restrict__ benv,
    const float* __restrict__ nrm, ushort* __restrict__ msg, float* __restrict__ out)
{
    __shared__ __align__(16) ushort sA[EPB * AST];   // 31744 B, multi-phase reuse
    __shared__ float sD1[EPB][12];
    __shared__ float sD2[EPB][28];
    __shared__ int sAe[EPB], sCtr[EPB], sNbr[EPB], sSlot[EPB];

    const int tid = threadIdx.x;
    const int wv = tid >> 6, lane = tid & 63;

    // ---------------- prologue: indices + frame + analytic l=2 Wigner ----------------
    if (tid < EPB) {
        int ae = act[blockIdx.x * EPB + tid];
        sAe[tid] = ae;
        sCtr[tid] = eidx[ae];
        sNbr[tid] = eidx[EE + ae];
        sSlot[tid] = eslot ? eslot[blockIdx.x * EPB + tid] : 0;

        float vx = evec[3*ae], vy = evec[3*ae+1], vz = evec[3*ae+2];
        float nnv = fmaxf(sqrtf(vx*vx + vy*vy + vz*vz), 1e-9f);
        float nx = vx/nnv, ny = vy/nnv, nz = vz/nnv;
        float ax, az;
        if (fabsf(nx) < 0.9f) { ax = 1.f; az = 0.f; } else { ax = 0.f; az = 1.f; }
        float adn = ax*nx + az*nz;
        float ux = ax - adn*nx, uy = -adn*ny, uz = az - adn*nz;
        float un = fmaxf(sqrtf(ux*ux + uy*uy + uz*uz), 1e-9f);
        ux /= un; uy /= un; uz /= un;
        float wx = uy*nz - uz*ny, wy = uz*nx - ux*nz, wz = ux*ny - uy*nx;

        sD1[tid][0] = ux; sD1[tid][1] = uy; sD1[tid][2] = uz;
        sD1[tid][3] = nx; sD1[tid][4] = ny; sD1[tid][5] = nz;
        sD1[tid][6] = wx; sD1[tid][7] = wy; sD1[tid][8] = wz;

        float d2[5][5];
        d2[0][0] = wz*ux + uz*wx;  d2[0][1] = wx*uy + ux*wy;  d2[0][2] = SQ3F*wy*uy;
        d2[0][3] = wy*uz + uy*wz;  d2[0][4] = wz*uz - wx*ux;
        d2[1][0] = uz*nx + nz*ux;  d2[1][1] = ux*ny + nx*uy;  d2[1][2] = SQ3F*uy*ny;
        d2[1][3] = uy*nz + ny*uz;  d2[1][4] = uz*nz - ux*nx;
        d2[2][0] = SQ3F*nz*nx;     d2[2][1] = SQ3F*nx*ny;     d2[2][2] = 1.5f*ny*ny - 0.5f;
        d2[2][3] = SQ3F*ny*nz;     d2[2][4] = 0.5f*SQ3F*(nz*nz - nx*nx);
        d2[3][0] = nz*wx + wz*nx;  d2[3][1] = nx*wy + wx*ny;  d2[3][2] = SQ3F*ny*wy;
        d2[3][3] = ny*wz + wy*nz;  d2[3][4] = nz*wz - nx*wx;
        d2[4][0] = wz*wx - uz*ux;  d2[4][1] = wx*wy - ux*uy;  d2[4][2] = 0.5f*SQ3F*(wy*wy - uy*uy);
        d2[4][3] = wy*wz - uy*uz;  d2[4][4] = 0.5f*(wz*wz - uz*uz - wx*wx + ux*ux);
#pragma unroll
        for (int n = 0; n < 5; ++n)
#pragma unroll
            for (int m = 0; m < 5; ++m) sD2[tid][5*n + m] = d2[n][m];
    }
    __syncthreads();

    // ---------------- prep 1: wave per edge (SLN + staging); sEb at row+64+planar ----------------
    for (int it = 0; it < 2; ++it) {
        const int e = it * 8 + wv;
        const int ae = sAe[e];
        const int ctr = sCtr[e], nbr = sNbr[e];
        ushort* row = sA + e * AST;
        ushort* rowEB = row + 64;    // planar indices [32..288) -> row offsets [96..352)
        const float* efr = ef + (size_t)ae * 288;

        float ev0 = efr[lane];
        float ev1 = efr[lane + 64];
        float ev2 = efr[lane + 128];
        float ev3 = efr[lane + 192];
        float ev4 = (lane < 32) ? efr[lane + 256] : 0.f;
        float s0 = 0.f, s0q = 0.f, q1 = 0.f, q2 = 0.f;
        if (lane < 32) { s0 = ev0; s0q = ev0*ev0; } else { q1 = ev0*ev0; }
        q1 += ev1*ev1;
        q2 += ev2*ev2 + ev3*ev3 + ev4*ev4;
#pragma unroll
        for (int m = 1; m < 64; m <<= 1) {
            s0  += __shfl_xor(s0, m);
            s0q += __shfl_xor(s0q, m);
            q1  += __shfl_xor(q1, m);
            q2  += __shfl_xor(q2, m);
        }
        float mu  = s0 * (1.f/32.f);
        float rs0 = rsqrtf(s0q*(1.f/32.f) - mu*mu + 1e-8f);
        float rs  = rsqrtf(0.5f*(q1*(1.f/96.f) + q2*(1.f/160.f)) + 1e-8f);

        if (lane >= 32) { int c = (lane-32)/3, m = (lane-32)%3; rowEB[32 + 32*m + c] = f2bf(ev0 * rs * g1e[c]); }
        { int k = lane+64;  int c = (k-32)/3,  m = (k-32)%3;  rowEB[32 + 32*m + c]  = f2bf(ev1 * rs * g1e[c]); }
        { int k = lane+128; int c = (k-128)/5, m = (k-128)%5; rowEB[128 + 32*m + c] = f2bf(ev2 * rs * g2e[c]); }
        { int k = lane+192; int c = (k-128)/5, m = (k-128)%5; rowEB[128 + 32*m + c] = f2bf(ev3 * rs * g2e[c]); }
        if (lane < 32) { int k = lane+256; int c = (k-128)/5, m = (k-128)%5; rowEB[128 + 32*m + c] = f2bf(ev4 * rs * g2e[c]); }

        if (lane < 32) {
            row[SEG0 + 32 + lane] = f2bf((ev0 - mu) * rs0 * g0e[lane] + b0e[lane]);
            row[SEG0 + lane]      = f2bf(nrm[(size_t)ctr*288 + lane]);
            row[SEG0 + 64 + lane] = f2bf(nrm[(size_t)nbr*288 + lane]);
        }
        {
            const float* lr = lat + (size_t)ae * 128;
            row[SEGL + lane]      = f2bf(lr[lane]);
            row[SEGL + 64 + lane] = f2bf(lr[lane + 64]);
        }
    }
    __syncthreads();

    // ---------------- prep 2: uniform rotate; sEb read-then-overwrite within wave ----------------
    {
        const int re = tid >> 5;        // edge 0..15
        const int rc = tid & 31;
        const float* bc = nrm + (size_t)sCtr[re] * 288;
        const float* bn = nrm + (size_t)sNbr[re] * 288;
        float c1v[3], c2v[5], n1v[3], n2v[5];
#pragma unroll
        for (int m = 0; m < 3; ++m) { c1v[m] = bc[32 + 32*m + rc]; n1v[m] = bn[32 + 32*m + rc]; }
#pragma unroll
        for (int m = 0; m < 5; ++m) { c2v[m] = bc[128 + 32*m + rc]; n2v[m] = bn[128 + 32*m + rc]; }
        ushort* row = sA + re * AST;
        const ushort* rowEB = row + 64;
        float e1v[3], e2v[5];
#pragma unroll
        for (int m = 0; m < 3; ++m) e1v[m] = bf2f(rowEB[32 + 32*m + rc]);
#pragma unroll
        for (int m = 0; m < 5; ++m) e2v[m] = bf2f(rowEB[128 + 32*m + rc]);
        asm volatile("" ::: "memory");   // keep sEb reads before any rotate writes
        float D1r[9], d2l[25];
#pragma unroll
        for (int i = 0; i < 9; ++i) D1r[i] = sD1[re][i];
#pragma unroll
        for (int i = 0; i < 25; ++i) d2l[i] = sD2[re][i];
#pragma unroll
        for (int p = 0; p < 3; ++p) {
            const int cc = rc + 32 * p;
            float x1v[3], x2v[5];
#pragma unroll
            for (int m = 0; m < 3; ++m) x1v[m] = (p == 0) ? c1v[m] : (p == 1) ? e1v[m] : n1v[m];
#pragma unroll
            for (int m = 0; m < 5; ++m) x2v[m] = (p == 0) ? c2v[m] : (p == 1) ? e2v[m] : n2v[m];
            float r0 = D1r[0]*x1v[0] + D1r[1]*x1v[1] + D1r[2]*x1v[2];
            float r1 = D1r[3]*x1v[0] + D1r[4]*x1v[1] + D1r[5]*x1v[2];
            float r2 = D1r[6]*x1v[0] + D1r[7]*x1v[1] + D1r[8]*x1v[2];
            float t[5];
#pragma unroll
            for (int m = 0; m < 5; ++m)
                t[m] = d2l[5*m+0]*x2v[0] + d2l[5*m+1]*x2v[1] + d2l[5*m+2]*x2v[2]
                     + d2l[5*m+3]*x2v[3] + d2l[5*m+4]*x2v[4];
            row[SEG0 + 96  + cc] = f2bf(r1);
            row[SEG0 + 192 + cc] = f2bf(t[2]);
            row[SEGP1 + cc]      = f2bf(r2);
            row[SEGP1 + 96 + cc] = f2bf(t[3]);
            row[SEGM1 + cc]      = f2bf(r0);
            row[SEGM1 + 96 + cc] = f2bf(t[1]);
            row[SEGP2 + cc]      = f2bf(t[4]);
            row[SEGM2 + cc]      = f2bf(t[0]);
        }
    }
    __syncthreads();

    // ---------------- MFMA GEMM: 28 tiles in registers, then Y -> sA[0..448) swizzled ----------------
    f32x4 pacc[4];
#pragma unroll
    for (int q = 0; q < 4; ++q) {
        const int t = wv + 8*q;
        if (t < 28) {
            int kbase, nch, pbase; float scale;
            if (t < 10)      { kbase = SEG0;  nch = 9;  scale = S0F; pbase = PK1 + t*9*512; }
            else if (t < 18) { kbase = SEGP1; nch = 12; scale = S1F; pbase = PK2 + (t-10)*12*512; }
            else if (t < 22) { kbase = SEGP2; nch = 6;  scale = S2F; pbase = PK3 + (t-18)*6*512; }
            else             { kbase = SEGL;  nch = 4;  scale = SEF; pbase = PK4 + (t-22)*4*512; }
            f32x4 acc = {0.f, 0.f, 0.f, 0.f};
            const ushort* pa = sA + (lane & 15) * AST + kbase + (lane >> 4) * 8;
            const ushort* pb = pk + pbase + lane * 8;
            for (int ch = 0; ch < nch; ++ch) {
                bf16x8 a = *reinterpret_cast<const bf16x8*>(pa + ch * 32);
                bf16x8 b = *reinterpret_cast<const bf16x8*>(pb + ch * 512);
                acc = __builtin_amdgcn_mfma_f32_16x16x32_bf16(a, b, acc, 0, 0, 0);
            }
            // scale + bias in registers (pre-barrier)
            int yoff = (t < 10) ? t*16 : (t < 18) ? 160+(t-10)*16 : (t < 22) ? 288+(t-18)*16 : 352+(t-22)*16;
            float bv = (t >= 22) ? benv[yoff + (lane & 15) - 352] : 0.f;
#pragma unroll
            for (int j = 0; j < 4; ++j) acc[j] = acc[j] * scale + bv;
            pacc[q] = acc;
        }
    }
    __syncthreads();   // all A-staging reads done -> rows reusable

#pragma unroll
    for (int q = 0; q < 4; ++q) {
        const int t = wv + 8*q;
        if (t < 28) {
            int yoff = (t < 10) ? t*16 : (t < 18) ? 160+(t-10)*16 : (t < 22) ? 288+(t-18)*16 : 352+(t-22)*16;
            const int col = yoff + (lane & 15);
            const int r0 = (lane >> 4) * 4;
#pragma unroll
            for (int j = 0; j < 4; ++j) {
                const int rr = r0 + j;
                sA[rr * AST + (col ^ (rr << 1))] = f2bf(pacc[q][j]);
            }
        }
    }
    __syncthreads();

    // ---------------- stage 2a: gates -> projA at rows [480..960) ----------------
    const int e2 = tid & 15, d = tid >> 4;   // d = channel 0..31
    {
        const int rowb = e2 * AST;
        const int sw = e2 << 1;
        auto LDY = [&](int x) { return bf2f(sA[rowb + (x ^ sw)]); };
        float y0v = LDY(Y0o + d);
        float scv = y0v * fsig(y0v);
        float gg1 = fsig(LDY(Y0o + 32 + d));
        float gg2 = fsig(LDY(Y0o + 64 + d));
        const int pabase = rowb + PA0 + 8*((d >> 3) ^ (e2 & 3)) + (d & 7);
        sA[pabase + 0*56] = f2bf(scv);
        sA[pabase + 1*56] = f2bf(LDY(Y1Mo  + d) * gg1);
        sA[pabase + 2*56] = f2bf(LDY(Y10o  + d) * gg1);
        sA[pabase + 3*56] = f2bf(LDY(Y1Po  + d) * gg1);
        sA[pabase + 4*56] = f2bf(LDY(Y2M2o + d) * gg2);
        sA[pabase + 5*56] = f2bf(LDY(Y2M1o + d) * gg2);
        sA[pabase + 6*56] = f2bf(LDY(Y20o  + d) * gg2);
        sA[pabase + 7*56] = f2bf(LDY(Y2P1o + d) * gg2);
        sA[pabase + 8*56] = f2bf(LDY(Y2P2o + d) * gg2);
    }
    __syncthreads();

    // ---------------- proj MFMA: 18 tiles in registers -> sP (f32) ----------------
    f32x4 pacc2[3];
#pragma unroll
    for (int q = 0; q < 3; ++q) {
        const int t = wv + 8*q;
        if (t < 18) {
            const int rt = t >> 1, ct = t & 1;
            const int wpi = (rt == 0) ? 0 : (rt < 4) ? 1 : 2;
            const int ar = lane & 15;
            bf16x8 a = *reinterpret_cast<const bf16x8*>(
                sA + ar*AST + PA0 + rt*56 + 8*((lane >> 4) ^ (ar & 3)));
            bf16x8 b = *reinterpret_cast<const bf16x8*>(pk + PKP + wpi*1024 + ct*512 + lane*8);
            f32x4 z = {0.f, 0.f, 0.f, 0.f};
            pacc2[q] = __builtin_amdgcn_mfma_f32_16x16x32_bf16(a, b, z, 0, 0, 0);
        }
    }
    __syncthreads();   // projA reads done

#pragma unroll
    for (int q = 0; q < 3; ++q) {
        const int t = wv + 8*q;
        if (t < 18) {
            const int rt = t >> 1, ct = t & 1;
            const int col = ct*16 + (lane & 15);
#pragma unroll
            for (int j = 0; j < 4; ++j) {
                const int ee = (lane >> 4)*4 + j;
                const int colSw = (col + 4*ee) & 31;
                float* fp = reinterpret_cast<float*>(sA + ee * AST);
                if (rt < 4) fp[rt*44 + colSw] = pacc2[q][j];
                else        fp[240 + (rt-4)*50 + colSw] = pacc2[q][j];
            }
        }
    }
    __syncthreads();

    // ---------------- stage 2b: rotate-back + env gate ----------------
    float m0v, o1[3], o2[5];
    {
        const int rowb = e2 * AST;
        const int sw = e2 << 1;
        auto LDY = [&](int x) { return bf2f(sA[rowb + (x ^ sw)]); };
        const float* fp = reinterpret_cast<const float*>(sA + rowb);
        const int cd = (d + 4*e2) & 31;
        float p0 = fp[cd];
        float p1v[3], p2v[5];
#pragma unroll
        for (int m = 0; m < 3; ++m) p1v[m] = fp[(1+m)*44 + cd];
#pragma unroll
        for (int m = 0; m < 5; ++m) p2v[m] = fp[240 + m*50 + cd];

        float wv0g = LDY(WENVo + d);
        float wv1g = LDY(WENVo + 32 + d) * SCF;
        float wv2g = LDY(WENVo + 64 + d) * SCF;
        m0v = (p0 * SCF + bp0[d]) * wv0g;
#pragma unroll
        for (int mm = 0; mm < 3; ++mm)
            o1[mm] = (sD1[e2][mm]*p1v[0] + sD1[e2][3+mm]*p1v[1] + sD1[e2][6+mm]*p1v[2]) * wv1g;
#pragma unroll
        for (int mm = 0; mm < 5; ++mm)
            o2[mm] = (sD2[e2][mm]*p2v[0] + sD2[e2][5+mm]*p2v[1] + sD2[e2][10+mm]*p2v[2]
                    + sD2[e2][15+mm]*p2v[3] + sD2[e2][20+mm]*p2v[4]) * wv2g;
    }

    if (msg) {
        __syncthreads();   // all sP/Y reads done -> rows reusable for msg staging
        ushort* stg = sA + e2 * AST;
        stg[d] = f2bf(m0v);
#pragma unroll
        for (int mm = 0; mm < 3; ++mm) stg[32 + 3*d + mm] = f2bf(o1[mm]);
#pragma unroll
        for (int mm = 0; mm < 5; ++mm) stg[128 + 5*d + mm] = f2bf(o2[mm]);
        __syncthreads();
        // coalesced copy: 16 rows x 288 ushorts
        const int e = tid >> 5, j = tid & 31;
        const ushort* src = sA + e * AST;
        ushort* dst = msg + (size_t)sSlot[e] * 288;
        *reinterpret_cast<bf16x8*>(dst + j*8) = *reinterpret_cast<const bf16x8*>(src + j*8);
        if (j < 4)
            *reinterpret_cast<bf16x8*>(dst + 256 + j*8) = *reinterpret_cast<const bf16x8*>(src + 256 + j*8);
    } else {
        float* ob = out + (size_t)sCtr[e2] * 288;
        atomicAdd(ob + d, COEFF * m0v);
#pragma unroll
        for (int mm = 0; mm < 3; ++mm) atomicAdd(ob + 32 + 3*d + mm, COEFF * o1[mm]);
#pragma unroll
        for (int mm = 0; mm < 5; ++mm) atomicAdd(ob + 128 + 5*d + mm, COEFF * o2[mm]);
    }
}

extern "C" void kernel_launch(void* const* d_in, const int* in_sizes, int n_in,
                              void* d_out, int out_size, void* d_ws, size_t ws_size,
                              hipStream_t stream)
{
    const float* latents = (const float*)d_in[0];
    const float* nf      = (const float*)d_in[1];
    const float* efe     = (const float*)d_in[2];
    const float* evec    = (const float*)d_in[3];
    const int*   eidx    = (const int*)d_in[5];
    const int*   act     = (const int*)d_in[6];
    const float* g0n = (const float*)d_in[7];
    const float* b0n = (const float*)d_in[8];
    const float* g1n = (const float*)d_in[9];
    const float* g2n = (const float*)d_in[10];
    const float* g0e = (const float*)d_in[11];
    const float* b0e = (const float*)d_in[12];
    const float* g1e = (const float*)d_in[13];
    const float* g2e = (const float*)d_in[14];
    const float* w0s = (const float*)d_in[15];
    const float* w01 = (const float*)d_in[16];
    const float* w02 = (const float*)d_in[17];
    const float* wr11 = (const float*)d_in[18];
    const float* wi11 = (const float*)d_in[19];
    const float* wr12 = (const float*)d_in[20];
    const float* wi12 = (const float*)d_in[21];
    const float* wr22 = (const float*)d_in[22];
    const float* wi22 = (const float*)d_in[23];
    const float* wp0 = (const float*)d_in[24];
    const float* bp0 = (const float*)d_in[25];
    const float* wp1 = (const float*)d_in[26];
    const float* wp2 = (const float*)d_in[27];
    const float* wenv = (const float*)d_in[28];
    const float* benv = (const float*)d_in[29];
    float* out = (float*)d_out;

    char* ws = (char*)d_ws;
    float* nrm  = (float*)(ws + WS_NRM);
    ushort* pkw = (ushort*)(ws + WS_PK);
    const bool use_msg = (ws_size >= WS_REQ);
    int* counts = (int*)(ws + WS_CNT);
    int* offs   = (int*)(ws + WS_OFF);
    int* curs   = (int*)(ws + WS_CUR);
    int* eslot  = (int*)(ws + WS_EL);
    ushort* msg = (ushort*)(ws + WS_MSG);

    hipMemsetAsync(counts, 0, NN * sizeof(int), stream);
    init_k<<<NNB + PKB + HSB, 256, 0, stream>>>(
        nf, g0n, b0n, g1n, g2n, nrm, use_msg ? nullptr : out,
        w0s, w01, w02, wr11, wi11, wr12, wi12, wr22, wi22, wenv, wp0, wp1, wp2, pkw,
        eidx, act, counts);
    if (use_msg) {
        scan_k<<<1, 1024, 0, stream>>>(counts, offs, curs);
        scatter_k<<<(EE + 255) / 256, 256, 0, stream>>>(eidx, act, curs, eslot);
    }
    edge_k<<<EE / EPB, 512, 0, stream>>>(latents, efe, evec, eidx, act,
        use_msg ? eslot : nullptr,
        g0e, b0e, g1e, g2e, pkw, bp0, benv, nrm, use_msg ? msg : nullptr, out);
    if (use_msg) {
        gather_k<<<(NN + 3) / 4, 256, 0, stream>>>(msg, offs, counts, nf, out);
    }
}